// Round 3
// baseline (2050.288 us; speedup 1.0000x reference)
//
#include <hip/hip_runtime.h>
#include <cmath>

typedef unsigned char u8;
typedef unsigned short u16;
typedef __attribute__((ext_vector_type(8))) short s8v;    // 8 bf16 = 4 VGPRs
typedef __attribute__((ext_vector_type(4))) float f32x4;  // MFMA acc

#define B 256
#define F 128
#define Q 4096
#define E 128
#define INV_TAU 5.0f
#define CAP 256               // compact entries per (e,b) row; binomial(4096,1/32) max ~180

// ---- ws layout (offsets in floats) ----
#define W_SCORES 0u            // B*Q = 1048576
#define W_CNT    1048576u      // B*Q
#define W_UNC    2097152u      // 4096
#define W_NLSE   2101248u      // 256
#define W_MOCO   2101504u
#define W_EASY   2101760u
#define W_HARD   2102016u
#define W_UB     2102272u      // 1 (padded 256)
#define W_INVN   2102528u      // E*Q = 524288
#define W_AF     2626816u      // bf16 E*B*F -> 2097152 floats
#define W_CNTB   4723968u      // Ec*256 ints (reserve 32768)
#define W_ENT    4756736u      // Ec*256*CAP uint2 -> Ec*131072 floats

// ---- out layout (floats) ----
#define O_MOCO   0u
#define O_LOGITS 1u            // (B, Q+1)
#define O_ELOSS  1048833u
#define O_EMASK  1048834u      // (B, Q)
#define O_HLOSS  2097410u
#define O_HMASK  2097411u      // (B, Q)

static __device__ __forceinline__ u16 f2bf(float x) {
    unsigned int u = __builtin_bit_cast(unsigned int, x);
    unsigned int r = (u + 0x7FFFu + ((u >> 16) & 1u)) >> 16;
    return (u16)r;
}

__global__ void k_zero(float* __restrict__ p) {
    p[(size_t)blockIdx.x * 256 + threadIdx.x] = 0.f;
}
__global__ void k_zeroi(int* __restrict__ p) {
    p[(size_t)blockIdx.x * 256 + threadIdx.x] = 0;
}

// one block (128 thr) per (e,b): masked l2-norm of teacher row -> bf16 A-fragments
// A-frag: af[(((e*16+bg)*4+kb)*64 + lane)*8 + j], bg=b>>4, m=b&15, lane=((f>>3)&3)*16+m, j=f&7
__global__ void k_afrag(const float* __restrict__ teacher, const u8* __restrict__ mask_t,
                        u16* __restrict__ af) {
    int eb = blockIdx.x;
    int e  = eb >> 8;
    int b  = eb & (B - 1);
    int f  = threadIdx.x;
    float v = mask_t[(size_t)eb * F + f] ? 0.f : teacher[b * F + f];
    float ss = v * v;
    #pragma unroll
    for (int o = 32; o > 0; o >>= 1) ss += __shfl_down(ss, o);
    __shared__ float s2[2];
    if ((threadIdx.x & 63) == 0) s2[threadIdx.x >> 6] = ss;
    __syncthreads();
    float d = fmaxf(sqrtf(s2[0] + s2[1]), 1e-12f);
    float t = v / d;
    int bg = b >> 4, m = b & 15;
    int kb = f >> 5, quad = (f >> 3) & 3, j = f & 7;
    int lane = quad * 16 + m;
    af[((((size_t)e * 16 + bg) * 4 + kb) * 64 + lane) * 8 + j] = f2bf(t);
}

// per (e,q): 1/(TAU * ||masked neg column||)
__global__ void k_invn(const float* __restrict__ neg, const u8* __restrict__ mask_n,
                       float* __restrict__ invn) {
    int e = blockIdx.x;
    int q = blockIdx.y * 256 + threadIdx.x;
    float ss = 0.f;
    #pragma unroll 4
    for (int f = 0; f < F; f++) {
        float v = mask_n[((size_t)e * F + f) * Q + q] ? 0.f : neg[f * Q + q];
        ss += v * v;
    }
    invn[e * Q + q] = INV_TAU / fmaxf(sqrtf(ss), 1e-12f);
}

// Fused: per (e, 32-q slab): build B-frags inline, MFMA sim tile (256b x 32q) into LDS,
// column(boot) softmax+entropy -> atomicAdd unc[q], extract smask entries -> compact buf.
__global__ void __launch_bounds__(256) k_fused(
        const u16* __restrict__ af, const float* __restrict__ neg,
        const u8* __restrict__ mask_n, const float* __restrict__ invn,
        const u8* __restrict__ boot, const u8* __restrict__ smask,
        float* __restrict__ unc, uint2* __restrict__ ent_buf,
        int* __restrict__ cnt_buf, int e0) {
    __shared__ u16 bfrag[2][4][64 * 8];     // 8 KB
    __shared__ float simt[256][36];         // 36 KB, pad 4 -> epilogue writes ~2-way
    __shared__ float sm[8][32], ssum[8][32], sent[8][32];
    __shared__ int scnt[8][32];
    int qb = blockIdx.x;                    // 0..127
    int el = blockIdx.y, e = e0 + el;
    int t = threadIdx.x;
    int q0 = qb * 32;

    // ---- stage B fragments (512 frag-slots, 2 per thread) ----
    #pragma unroll
    for (int s = 0; s < 2; s++) {
        int slot = t + 256 * s;
        int qg = slot >> 8;
        int r = slot & 255;
        int kb = r >> 6, lane = r & 63;
        int q = q0 + qg * 16 + (lane & 15);
        int fb = kb * 32 + (lane >> 4) * 8;
        float iv = invn[e * Q + q];
        u16 tmp[8];
        #pragma unroll
        for (int j = 0; j < 8; j++) {
            int f = fb + j;
            u8 mm = mask_n[((size_t)e * F + f) * Q + q];
            float v = mm ? 0.f : neg[(size_t)f * Q + q] * iv;
            tmp[j] = f2bf(v);
        }
        *(s8v*)&bfrag[qg][kb][lane * 8] = *(const s8v*)tmp;
    }
    __syncthreads();

    // ---- MFMA: wave handles bg in {4w..4w+3} x 2 qg ----
    int wave = t >> 6, lane = t & 63;
    int colb = lane & 15, quad = lane >> 4;
    #pragma unroll
    for (int bgi = 0; bgi < 4; bgi++) {
        int bg = wave * 4 + bgi;
        s8v a[4];
        #pragma unroll
        for (int kb = 0; kb < 4; kb++)
            a[kb] = *(const s8v*)&af[((((size_t)e * 16 + bg) * 4 + kb) * 64 + lane) * 8];
        #pragma unroll
        for (int qg = 0; qg < 2; qg++) {
            f32x4 acc = {0.f, 0.f, 0.f, 0.f};
            #pragma unroll
            for (int kb = 0; kb < 4; kb++) {
                s8v bv = *(const s8v*)&bfrag[qg][kb][lane * 8];
                acc = __builtin_amdgcn_mfma_f32_16x16x32_bf16(a[kb], bv, acc, 0, 0, 0);
            }
            int col = qg * 16 + colb;
            int r0 = bg * 16 + quad * 4;
            #pragma unroll
            for (int r = 0; r < 4; r++) simt[r0 + r][col] = acc[r];
        }
    }
    __syncthreads();

    // ---- entropy: column softmax over 256 b (8 segs x 32 b), q = q0 + tq ----
    int tq = t & 31, seg = t >> 5;
    int q = q0 + tq;
    float z[32];
    {
        const u8* bm = boot + ((size_t)e * B + seg * 32) * Q + q;
        float m = -INFINITY;
        unsigned mk = 0u;
        #pragma unroll
        for (int bi = 0; bi < 32; bi++) {
            z[bi] = simt[seg * 32 + bi][tq];
            if (bm[(size_t)bi * Q]) { mk |= 1u << bi; m = fmaxf(m, z[bi]); }
        }
        float s = 0.f;
        #pragma unroll
        for (int bi = 0; bi < 32; bi++)
            if ((mk >> bi) & 1) s += __expf(z[bi] - m);
        sm[seg][tq] = m; ssum[seg][tq] = s; scnt[seg][tq] = __popc(mk);
        __syncthreads();
        float M = -INFINITY; int C = 0;
        #pragma unroll
        for (int i = 0; i < 8; i++) { M = fmaxf(M, sm[i][tq]); C += scnt[i][tq]; }
        float S = 0.f;
        #pragma unroll
        for (int i = 0; i < 8; i++) {
            float mi = sm[i][tq];
            if (mi != -INFINITY) S += ssum[i][tq] * __expf(mi - M);
        }
        if (M == -INFINITY) M = 0.f;          // ref guard (fully-masked column)
        float invS = 1.f / fmaxf(S, 1e-30f);
        const float P0 = 1e-7f;
        const float C0 = 1.61180954e-6f;      // -P0*log(P0)
        float ent = 0.f;
        #pragma unroll
        for (int bi = 0; bi < 32; bi++) {
            if ((mk >> bi) & 1) {
                float p = __expf(z[bi] - M) * invS + P0;
                ent -= p * __logf(p);
            } else ent += C0;
        }
        sent[seg][tq] = ent;
        __syncthreads();
        if (seg == 0) {
            float tot = 0.f;
            #pragma unroll
            for (int i = 0; i < 8; i++) tot += sent[i][tq];
            atomicAdd(&unc[q], tot / fmaxf((float)C, 1.f));
        }
    }

    // ---- extract score_mask entries (z[] still holds this thread's column values) ----
    {
        const u8* sk = smask + ((size_t)e * B + seg * 32) * Q + q;
        #pragma unroll
        for (int bi = 0; bi < 32; bi++) {
            if (sk[(size_t)bi * Q]) {
                int b = seg * 32 + bi;
                int idx = atomicAdd(&cnt_buf[el * B + b], 1);
                if (idx < CAP) {
                    uint2 en;
                    en.x = (unsigned)q;
                    en.y = __builtin_bit_cast(unsigned, z[bi]);
                    ent_buf[((size_t)(el * B + b)) * CAP + idx] = en;
                }
            }
        }
    }
}

// block per b: replay compact entries -> row softmax -> accumulate scores/cnt rows
__global__ void k_scores(const uint2* __restrict__ ent_buf, const int* __restrict__ cnt_buf,
                         float* __restrict__ sacc, float* __restrict__ cacc, int ecnt) {
    __shared__ float srow[Q];
    __shared__ float crow[Q];
    __shared__ float red[256];
    int b = blockIdx.x, t = threadIdx.x;
    #pragma unroll
    for (int j = 0; j < 16; j++) { srow[t + 256 * j] = 0.f; crow[t + 256 * j] = 0.f; }
    __syncthreads();
    for (int el = 0; el < ecnt; el++) {
        int c = cnt_buf[el * B + b];
        if (c > CAP) c = CAP;
        if (c == 0) continue;
        uint2 en; float zz = -INFINITY;
        if (t < c) { en = ent_buf[((size_t)(el * B + b)) * CAP + t]; zz = __builtin_bit_cast(float, en.y); }
        red[t] = zz; __syncthreads();
        for (int s = 128; s > 0; s >>= 1) { if (t < s) red[t] = fmaxf(red[t], red[t + s]); __syncthreads(); }
        float M = red[0]; __syncthreads();
        float ex = (t < c) ? expf(zz - M) : 0.f;
        red[t] = ex; __syncthreads();
        for (int s = 128; s > 0; s >>= 1) { if (t < s) red[t] += red[t + s]; __syncthreads(); }
        float iS = 1.f / fmaxf(red[0], 1e-30f);
        __syncthreads();
        if (t < c) { srow[en.x] += ex * iS; crow[en.x] += 1.f; }
        __syncthreads();
    }
    #pragma unroll
    for (int j = 0; j < 16; j++) {
        int qq = t + 256 * j;
        sacc[(size_t)b * Q + qq] += srow[qq];
        cacc[(size_t)b * Q + qq] += crow[qq];
    }
}

__global__ void k_finscores(float* __restrict__ sacc, const float* __restrict__ cacc) {
    int idx = blockIdx.x * 256 + threadIdx.x;
    sacc[idx] = sacc[idx] / fmaxf(cacc[idx], 1.f);
}

// block per b: logits row (pos + neg) scaled by 1/TAU
__global__ void k_logits(const float* __restrict__ query, const float* __restrict__ key,
                         const float* __restrict__ neg, float* __restrict__ out) {
    __shared__ float qrow[F];
    __shared__ float red[256];
    int b = blockIdx.x, t = threadIdx.x;
    float pp = 0.f;
    if (t < F) { float qv = query[b * F + t]; qrow[t] = qv; pp = qv * key[b * F + t]; }
    red[t] = pp;
    __syncthreads();
    for (int s = 128; s > 0; s >>= 1) { if (t < s) red[t] += red[t + s]; __syncthreads(); }
    float pos = red[0];
    float acc[16];
    #pragma unroll
    for (int j = 0; j < 16; j++) acc[j] = 0.f;
    for (int f = 0; f < F; f++) {
        float a = qrow[f];
        const float* np_ = neg + (size_t)f * Q + t;
        #pragma unroll
        for (int j = 0; j < 16; j++) acc[j] = fmaf(a, np_[256 * j], acc[j]);
    }
    float* row = out + O_LOGITS + (size_t)b * (Q + 1);
    #pragma unroll
    for (int j = 0; j < 16; j++) row[1 + t + 256 * j] = acc[j] * INV_TAU;
    if (t == 0) row[0] = pos * INV_TAU;
}

// block per b: moco part (full-row LSE - z0) and neg-only LSE
__global__ void k_rowstats(const float* __restrict__ out, float* __restrict__ moco_part,
                           float* __restrict__ nlse) {
    __shared__ float red[256];
    int b = blockIdx.x, t = threadIdx.x;
    const float* row = out + O_LOGITS + (size_t)b * (Q + 1);
    float m = -INFINITY, mn = -INFINITY;
    for (int j = 0; j < 17; j++) {
        int i = t + 256 * j;
        if (i < Q + 1) { float zz = row[i]; m = fmaxf(m, zz); if (i >= 1) mn = fmaxf(mn, zz); }
    }
    red[t] = m; __syncthreads();
    for (int s = 128; s > 0; s >>= 1) { if (t < s) red[t] = fmaxf(red[t], red[t + s]); __syncthreads(); }
    float M = red[0]; __syncthreads();
    red[t] = mn; __syncthreads();
    for (int s = 128; s > 0; s >>= 1) { if (t < s) red[t] = fmaxf(red[t], red[t + s]); __syncthreads(); }
    float Mn = red[0]; __syncthreads();
    float s1 = 0.f, s2 = 0.f;
    for (int j = 0; j < 17; j++) {
        int i = t + 256 * j;
        if (i < Q + 1) { float zz = row[i]; s1 += expf(zz - M); if (i >= 1) s2 += expf(zz - Mn); }
    }
    red[t] = s1; __syncthreads();
    for (int s = 128; s > 0; s >>= 1) { if (t < s) red[t] += red[t + s]; __syncthreads(); }
    float S = red[0]; __syncthreads();
    red[t] = s2; __syncthreads();
    for (int s = 128; s > 0; s >>= 1) { if (t < s) red[t] += red[t + s]; __syncthreads(); }
    float Sn = red[0];
    if (t == 0) { moco_part[b] = M + logf(S) - row[0]; nlse[b] = Mn + logf(Sn); }
}

// normalize unc (/E), bitonic sort 4096, median per np.quantile 'linear'
__global__ void k_median(float* __restrict__ unc, float* __restrict__ ubp) {
    __shared__ float sd[4096];
    int t = threadIdx.x;
    #pragma unroll
    for (int j = 0; j < 4; j++) {
        int q = t + 1024 * j;
        float u = unc[q] * (1.f / 128.f);
        unc[q] = u; sd[q] = u;
    }
    __syncthreads();
    for (int k = 2; k <= 4096; k <<= 1) {
        for (int j = k >> 1; j > 0; j >>= 1) {
            #pragma unroll
            for (int base = 0; base < 4; base++) {
                int i = t + 1024 * base;
                int ixj = i ^ j;
                if (ixj > i) {
                    bool up = ((i & k) == 0);
                    float x = sd[i], y = sd[ixj];
                    if ((x > y) == up) { sd[i] = y; sd[ixj] = x; }
                }
            }
            __syncthreads();
        }
    }
    if (t == 0) { float a = sd[2047], b2 = sd[2048]; ubp[0] = a + 0.5f * (b2 - a); }
}

// per (b, mode): argmax of scores among allowed q (lowest-index ties), mask + loss part
__global__ void k_select(float* __restrict__ out, const float* __restrict__ scores,
                         const float* __restrict__ unc, const float* __restrict__ ubp,
                         const float* __restrict__ nlse, float* __restrict__ easy_part,
                         float* __restrict__ hard_part) {
    __shared__ float rv[256];
    __shared__ int ri[256];
    __shared__ int bshare;
    int b = blockIdx.x, mode = blockIdx.y, t = threadIdx.x;
    float ub = ubp[0];
    float bv = -INFINITY; int bidx = Q;
    #pragma unroll
    for (int j = 0; j < 16; j++) {
        int q = t + 256 * j;
        float u = unc[q];
        bool ok = (mode == 0) ? (u <= ub) : (u >= ub);
        if (ok) {
            float v = scores[(size_t)b * Q + q];
            if (v > bv || (v == bv && q < bidx)) { bv = v; bidx = q; }
        }
    }
    rv[t] = bv; ri[t] = bidx; __syncthreads();
    for (int s = 128; s > 0; s >>= 1) {
        if (t < s) {
            float v2 = rv[t + s]; int i2 = ri[t + s];
            if (v2 > rv[t] || (v2 == rv[t] && i2 < ri[t])) { rv[t] = v2; ri[t] = i2; }
        }
        __syncthreads();
    }
    if (t == 0) {
        int best = ri[0]; bshare = best;
        float zz = out[O_LOGITS + (size_t)b * (Q + 1) + 1 + best];
        float loss = nlse[b] - zz;
        (mode == 0 ? easy_part : hard_part)[b] = loss;
    }
    __syncthreads();
    int best = bshare;
    float* mrow = out + (mode == 0 ? O_EMASK : O_HMASK) + (size_t)b * Q;
    #pragma unroll
    for (int j = 0; j < 16; j++) { int q = t + 256 * j; mrow[q] = (q == best) ? 1.f : 0.f; }
}

__global__ void k_scalars(const float* __restrict__ moco, const float* __restrict__ easyp,
                          const float* __restrict__ hardp, float* __restrict__ out) {
    __shared__ float red[256];
    int t = threadIdx.x;
    red[t] = moco[t]; __syncthreads();
    for (int s = 128; s > 0; s >>= 1) { if (t < s) red[t] += red[t + s]; __syncthreads(); }
    if (t == 0) out[O_MOCO] = red[0] / 256.f;
    __syncthreads();
    red[t] = easyp[t]; __syncthreads();
    for (int s = 128; s > 0; s >>= 1) { if (t < s) red[t] += red[t + s]; __syncthreads(); }
    if (t == 0) out[O_ELOSS] = red[0] / 256.f;
    __syncthreads();
    red[t] = hardp[t]; __syncthreads();
    for (int s = 128; s > 0; s >>= 1) { if (t < s) red[t] += red[t + s]; __syncthreads(); }
    if (t == 0) out[O_HLOSS] = red[0] / 256.f;
}

extern "C" void kernel_launch(void* const* d_in, const int* in_sizes, int n_in,
                              void* d_out, int out_size, void* d_ws, size_t ws_size,
                              hipStream_t stream) {
    const float* query   = (const float*)d_in[0];
    const float* key     = (const float*)d_in[1];
    const float* teacher = (const float*)d_in[2];
    const float* neg     = (const float*)d_in[3];
    const u8* mask_t     = (const u8*)d_in[4];
    const u8* mask_n     = (const u8*)d_in[5];
    const u8* score_mask = (const u8*)d_in[6];
    const u8* boot_mask  = (const u8*)d_in[7];
    float* out = (float*)d_out;
    float* ws  = (float*)d_ws;

    long ws_floats = (long)(ws_size / 4);
    int Ec = (int)((ws_floats - (long)W_ENT) / (long)(B * CAP * 2));
    if (Ec > E) Ec = E;
    if (Ec < 1) Ec = 1;

    u16* af = (u16*)(ws + W_AF);
    int* cnt_buf = (int*)(ws + W_CNTB);
    uint2* ent_buf = (uint2*)(ws + W_ENT);

    // zero scores + cnt + unc (contiguous 2101248 floats)
    k_zero<<<2101248 / 256, 256, 0, stream>>>(ws + W_SCORES);
    k_afrag<<<E * B, 128, 0, stream>>>(teacher, mask_t, af);
    k_invn<<<dim3(E, Q / 256), 256, 0, stream>>>(neg, mask_n, ws + W_INVN);
    k_logits<<<B, 256, 0, stream>>>(query, key, neg, out);
    k_rowstats<<<B, 256, 0, stream>>>(out, ws + W_MOCO, ws + W_NLSE);

    for (int e0 = 0; e0 < E; e0 += Ec) {
        int ecnt = (E - e0 < Ec) ? (E - e0) : Ec;
        k_zeroi<<<ecnt, 256, 0, stream>>>(cnt_buf);
        k_fused<<<dim3(Q / 32, ecnt), 256, 0, stream>>>(
            af, neg, mask_n, ws + W_INVN, boot_mask, score_mask,
            ws + W_UNC, ent_buf, cnt_buf, e0);
        k_scores<<<B, 256, 0, stream>>>(ent_buf, cnt_buf, ws + W_SCORES, ws + W_CNT, ecnt);
    }

    k_finscores<<<(B * Q) / 256, 256, 0, stream>>>(ws + W_SCORES, ws + W_CNT);
    k_median<<<1, 1024, 0, stream>>>(ws + W_UNC, ws + W_UB);
    k_select<<<dim3(B, 2), 256, 0, stream>>>(out, ws + W_SCORES, ws + W_UNC, ws + W_UB,
                                             ws + W_NLSE, ws + W_EASY, ws + W_HARD);
    k_scalars<<<1, 256, 0, stream>>>(ws + W_MOCO, ws + W_EASY, ws + W_HARD, out);
}

// Round 4
// 1442.532 us; speedup vs baseline: 1.4213x; 1.4213x over previous
//
#include <hip/hip_runtime.h>
#include <cmath>

typedef unsigned char u8;
typedef unsigned short u16;
typedef unsigned int u32;
typedef __attribute__((ext_vector_type(8))) short s8v;    // 8 bf16 = 4 VGPRs
typedef __attribute__((ext_vector_type(4))) float f32x4;  // MFMA acc

#define B 256
#define F 128
#define Q 4096
#define E 128
#define QW 128               // Q/32 words per row
#define INV_TAU 5.0f
#define CAP 256              // compact entries per (e,b); binomial(4096,1/32) max ~180

// ---- ws layout (offsets in floats) ----
#define W_SCORES 0u            // B*Q = 1048576
#define W_CNT    1048576u      // B*Q
#define W_UNC    2097152u      // 4096
#define W_NLSE   2101248u      // 256
#define W_MOCO   2101504u
#define W_EASY   2101760u
#define W_HARD   2102016u
#define W_UB     2102272u      // 1 (padded 256)
#define W_INVN   2102528u      // E*Q = 524288
#define W_AF     2626816u      // bf16 E*B*F -> 2097152 floats
#define W_PB     4723968u      // packed boot  E*QW*B words = 4194304
#define W_PS     8918272u      // packed smask E*QW*B words = 4194304
#define W_PN     13112576u     // packed mask_n E*QW*F words = 2097152
#define W_CNTB   15209728u     // Ec*256 ints (reserve 32768)
#define W_ENT    15242496u     // Ec*256*CAP uint2 -> Ec*131072 floats

// ---- out layout (floats) ----
#define O_MOCO   0u
#define O_LOGITS 1u            // (B, Q+1)
#define O_ELOSS  1048833u
#define O_EMASK  1048834u      // (B, Q)
#define O_HLOSS  2097410u
#define O_HMASK  2097411u      // (B, Q)

static __device__ __forceinline__ u16 f2bf(float x) {
    unsigned int u = __builtin_bit_cast(unsigned int, x);
    unsigned int r = (u + 0x7FFFu + ((u >> 16) & 1u)) >> 16;
    return (u16)r;
}

__global__ void k_zero(float* __restrict__ p) {
    p[(size_t)blockIdx.x * 256 + threadIdx.x] = 0.f;
}
__global__ void k_zeroi(int* __restrict__ p) {
    p[(size_t)blockIdx.x * 256 + threadIdx.x] = 0;
}

// ---- bit-pack bool mask (N rows x Q bytes) -> transposed words out[e][qw][r]
// block: 64 rows x 512 q. LDS stride 133 words (odd) -> conflict-free transpose.
__global__ void __launch_bounds__(256) k_pack(const u8* __restrict__ in,
                                              u32* __restrict__ out, int Rin) {
    __shared__ u32 lds[64 * 133];
    int t = threadIdx.x;
    int r0 = blockIdx.x * 64;
    int q0 = blockIdx.y * 512;
    int qw0 = q0 >> 5;
    #pragma unroll
    for (int i = 0; i < 8; i++) {
        int w = i * 256 + t;               // uint4 index; 32 per row
        int row = w >> 5, c = w & 31;
        uint4 v = *(const uint4*)&in[(size_t)(r0 + row) * Q + q0 + c * 16];
        int base = row * 133 + c * 4;
        lds[base] = v.x; lds[base + 1] = v.y; lds[base + 2] = v.z; lds[base + 3] = v.w;
    }
    __syncthreads();
    int e = r0 / Rin, rr = r0 % Rin;
    #pragma unroll
    for (int k = 0; k < 4; k++) {
        int qw = (t >> 6) + k * 4;         // 0..15
        int r = t & 63;
        u32 w = 0;
        #pragma unroll
        for (int j = 0; j < 8; j++) {
            u32 u = lds[r * 133 + qw * 8 + j];
            w |= ((u & 1u) | ((u >> 7) & 2u) | ((u >> 14) & 4u) | ((u >> 21) & 8u)) << (j * 4);
        }
        out[((size_t)e * QW + qw0 + qw) * Rin + rr + r] = w;
    }
}

// one block (128 thr) per (e,b): masked l2-norm of teacher row -> bf16 A-fragments
__global__ void k_afrag(const float* __restrict__ teacher, const u8* __restrict__ mask_t,
                        u16* __restrict__ af) {
    int eb = blockIdx.x;
    int e  = eb >> 8;
    int b  = eb & (B - 1);
    int f  = threadIdx.x;
    float v = mask_t[(size_t)eb * F + f] ? 0.f : teacher[b * F + f];
    float ss = v * v;
    #pragma unroll
    for (int o = 32; o > 0; o >>= 1) ss += __shfl_down(ss, o);
    __shared__ float s2[2];
    if ((threadIdx.x & 63) == 0) s2[threadIdx.x >> 6] = ss;
    __syncthreads();
    float d = fmaxf(sqrtf(s2[0] + s2[1]), 1e-12f);
    float t = v / d;
    int bg = b >> 4, m = b & 15;
    int kb = f >> 5, quad = (f >> 3) & 3, j = f & 7;
    int lane = quad * 16 + m;
    af[((((size_t)e * 16 + bg) * 4 + kb) * 64 + lane) * 8 + j] = f2bf(t);
}

// per (e,q): 1/(TAU * ||masked neg column||)
__global__ void k_invn(const float* __restrict__ neg, const u8* __restrict__ mask_n,
                       float* __restrict__ invn) {
    int e = blockIdx.x;
    int q = blockIdx.y * 256 + threadIdx.x;
    float ss = 0.f;
    #pragma unroll 4
    for (int f = 0; f < F; f++) {
        float v = mask_n[((size_t)e * F + f) * Q + q] ? 0.f : neg[f * Q + q];
        ss += v * v;
    }
    invn[e * Q + q] = INV_TAU / fmaxf(sqrtf(ss), 1e-12f);
}

// Fused: per (e, 32-q slab): B-frags inline, MFMA in registers, cross-lane column
// softmax+entropy (boot bits), popc-reserved extraction of smask entries.
__global__ void __launch_bounds__(256) k_fused(
        const u16* __restrict__ af, const float* __restrict__ neg,
        const u32* __restrict__ pn, const float* __restrict__ invn,
        const u32* __restrict__ pb, const u32* __restrict__ ps,
        float* __restrict__ unc, uint2* __restrict__ ent_buf,
        int* __restrict__ cnt_buf, int e0) {
    __shared__ u16 bfrag[2][4][64 * 8];                       // 8 KB
    __shared__ __align__(16) u32 bword[256];                  // boot words
    __shared__ __align__(16) u32 sword[256];                  // smask words
    __shared__ int sbase[256];
    __shared__ float mstat[4][32], sstat[4][32], cstat[4][32], estat[4][32];
    __shared__ float carr[32];

    int qb = blockIdx.x;                  // == qw for this slab
    int el = blockIdx.y, e = e0 + el;
    int t = threadIdx.x;
    int q0 = qb * 32;

    // mask words for this slab (fully coalesced, 2 KB)
    bword[t] = pb[((size_t)e * QW + qb) * B + t];
    sword[t] = ps[((size_t)e * QW + qb) * B + t];

    // ---- stage B fragments (512 slots, 2/thread) ----
    #pragma unroll
    for (int s = 0; s < 2; s++) {
        int slot = t + 256 * s;
        int qg = slot >> 8;
        int r = slot & 255;
        int kb = r >> 6, lane2 = r & 63;
        int q = q0 + qg * 16 + (lane2 & 15);
        int fb = kb * 32 + (lane2 >> 4) * 8;
        float iv = invn[e * Q + q];
        u16 tmp[8];
        #pragma unroll
        for (int j = 0; j < 8; j++) {
            u32 bit = (pn[((size_t)e * QW + qb) * F + fb + j] >> (q & 31)) & 1u;
            float v = bit ? 0.f : neg[(size_t)(fb + j) * Q + q] * iv;
            tmp[j] = f2bf(v);
        }
        *(s8v*)&bfrag[qg][kb][lane2 * 8] = *(const s8v*)tmp;
    }
    __syncthreads();

    // ---- MFMA: wave w covers b in [w*64, w*64+64), both qg columns ----
    int wave = t >> 6, lane = t & 63;
    int colb = lane & 15, quad = lane >> 4;
    f32x4 acc[4][2];
    #pragma unroll
    for (int bgi = 0; bgi < 4; bgi++) {
        int bg = wave * 4 + bgi;
        s8v a[4];
        #pragma unroll
        for (int kb = 0; kb < 4; kb++)
            a[kb] = *(const s8v*)&af[((((size_t)e * 16 + bg) * 4 + kb) * 64 + lane) * 8];
        #pragma unroll
        for (int qg = 0; qg < 2; qg++) {
            f32x4 c4 = {0.f, 0.f, 0.f, 0.f};
            #pragma unroll
            for (int kb = 0; kb < 4; kb++) {
                s8v bv = *(const s8v*)&bfrag[qg][kb][lane * 8];
                c4 = __builtin_amdgcn_mfma_f32_16x16x32_bf16(a[kb], bv, c4, 0, 0, 0);
            }
            acc[bgi][qg] = c4;
        }
    }

    // boot words for this lane's 16 b-rows (kept in regs)
    u32 bwr[4][4];
    #pragma unroll
    for (int bgi = 0; bgi < 4; bgi++) {
        int b0 = (wave * 4 + bgi) * 16 + quad * 4;
        uint4 v = *(const uint4*)&bword[b0];
        bwr[bgi][0] = v.x; bwr[bgi][1] = v.y; bwr[bgi][2] = v.z; bwr[bgi][3] = v.w;
    }

    // ---- phase A: masked max per column ----
    float mloc[2] = {-INFINITY, -INFINITY};
    #pragma unroll
    for (int bgi = 0; bgi < 4; bgi++)
        #pragma unroll
        for (int r = 0; r < 4; r++)
            #pragma unroll
            for (int qg = 0; qg < 2; qg++)
                if ((bwr[bgi][r] >> (qg * 16 + colb)) & 1u)
                    mloc[qg] = fmaxf(mloc[qg], acc[bgi][qg][r]);
    #pragma unroll
    for (int qg = 0; qg < 2; qg++) {
        mloc[qg] = fmaxf(mloc[qg], __shfl_xor(mloc[qg], 16));
        mloc[qg] = fmaxf(mloc[qg], __shfl_xor(mloc[qg], 32));
    }
    if (quad == 0) { mstat[wave][colb] = mloc[0]; mstat[wave][16 + colb] = mloc[1]; }
    __syncthreads();
    float Mg[2];
    #pragma unroll
    for (int qg = 0; qg < 2; qg++) {
        int col = qg * 16 + colb;
        float M = fmaxf(fmaxf(mstat[0][col], mstat[1][col]),
                        fmaxf(mstat[2][col], mstat[3][col]));
        Mg[qg] = (M == -INFINITY) ? 0.f : M;
    }

    // ---- phase B: masked exp-sum + count ----
    float sloc[2] = {0.f, 0.f}, cloc[2] = {0.f, 0.f};
    #pragma unroll
    for (int bgi = 0; bgi < 4; bgi++)
        #pragma unroll
        for (int r = 0; r < 4; r++)
            #pragma unroll
            for (int qg = 0; qg < 2; qg++)
                if ((bwr[bgi][r] >> (qg * 16 + colb)) & 1u) {
                    sloc[qg] += __expf(acc[bgi][qg][r] - Mg[qg]);
                    cloc[qg] += 1.f;
                }
    #pragma unroll
    for (int qg = 0; qg < 2; qg++) {
        sloc[qg] += __shfl_xor(sloc[qg], 16); sloc[qg] += __shfl_xor(sloc[qg], 32);
        cloc[qg] += __shfl_xor(cloc[qg], 16); cloc[qg] += __shfl_xor(cloc[qg], 32);
    }
    if (quad == 0) {
        sstat[wave][colb] = sloc[0]; sstat[wave][16 + colb] = sloc[1];
        cstat[wave][colb] = cloc[0]; cstat[wave][16 + colb] = cloc[1];
    }
    __syncthreads();
    float invS[2];
    #pragma unroll
    for (int qg = 0; qg < 2; qg++) {
        int col = qg * 16 + colb;
        float S = sstat[0][col] + sstat[1][col] + sstat[2][col] + sstat[3][col];
        invS[qg] = 1.f / fmaxf(S, 1e-30f);
        if (wave == 0 && quad == 0)
            carr[col] = cstat[0][col] + cstat[1][col] + cstat[2][col] + cstat[3][col];
    }

    // ---- phase C: entropy ----
    const float P0 = 1e-7f;
    const float C0 = 1.61180954e-6f;      // -P0*log(P0)
    float eloc[2] = {0.f, 0.f};
    #pragma unroll
    for (int bgi = 0; bgi < 4; bgi++)
        #pragma unroll
        for (int r = 0; r < 4; r++)
            #pragma unroll
            for (int qg = 0; qg < 2; qg++) {
                if ((bwr[bgi][r] >> (qg * 16 + colb)) & 1u) {
                    float p = __expf(acc[bgi][qg][r] - Mg[qg]) * invS[qg] + P0;
                    eloc[qg] -= p * __logf(p);
                } else {
                    eloc[qg] += C0;
                }
            }
    #pragma unroll
    for (int qg = 0; qg < 2; qg++) {
        eloc[qg] += __shfl_xor(eloc[qg], 16); eloc[qg] += __shfl_xor(eloc[qg], 32);
    }
    if (quad == 0) { estat[wave][colb] = eloc[0]; estat[wave][16 + colb] = eloc[1]; }

    // ---- extraction reservation (per-b popc) ----
    {
        u32 sw = sword[t];
        int n = __popc(sw);
        int base = 0;
        if (n) base = atomicAdd(&cnt_buf[el * B + t], n);
        sbase[t] = base;
    }
    __syncthreads();

    if (t < 32) {
        float tot = estat[0][t] + estat[1][t] + estat[2][t] + estat[3][t];
        atomicAdd(&unc[q0 + t], tot / fmaxf(carr[t], 1.f));
    }

    // ---- scatter compact entries ----
    #pragma unroll
    for (int bgi = 0; bgi < 4; bgi++) {
        int b0 = (wave * 4 + bgi) * 16 + quad * 4;
        uint4 sv = *(const uint4*)&sword[b0];
        u32 svr[4] = {sv.x, sv.y, sv.z, sv.w};
        #pragma unroll
        for (int r = 0; r < 4; r++)
            #pragma unroll
            for (int qg = 0; qg < 2; qg++) {
                int c = qg * 16 + colb;
                u32 w = svr[r];
                if ((w >> c) & 1u) {
                    int pos = sbase[b0 + r] + __popc(w & ((1u << c) - 1u));
                    if (pos < CAP) {
                        uint2 en;
                        en.x = (unsigned)(q0 + c);
                        en.y = __builtin_bit_cast(unsigned, acc[bgi][qg][r]);
                        ent_buf[((size_t)(el * B + b0 + r)) * CAP + pos] = en;
                    }
                }
            }
    }
}

// block per b: wave-per-el replay of compact entries -> row softmax -> scores/cnt
__global__ void __launch_bounds__(256) k_scores(
        const uint2* __restrict__ ent_buf, const int* __restrict__ cnt_buf,
        float* __restrict__ sacc, float* __restrict__ cacc, int ecnt) {
    __shared__ float srow[Q];
    __shared__ float crow[Q];
    int b = blockIdx.x, t = threadIdx.x;
    #pragma unroll
    for (int j = 0; j < 16; j++) { srow[t + 256 * j] = 0.f; crow[t + 256 * j] = 0.f; }
    __syncthreads();
    int wave = t >> 6, lane = t & 63;
    for (int el = wave; el < ecnt; el += 4) {
        int c = cnt_buf[el * B + b];
        if (c > CAP) c = CAP;
        if (c == 0) continue;
        const uint2* p = ent_buf + (size_t)(el * B + b) * CAP;
        uint2 ev[4]; int ne = 0;
        float m = -INFINITY;
        for (int i = lane; i < c; i += 64) {
            ev[ne] = p[i];
            m = fmaxf(m, __builtin_bit_cast(float, ev[ne].y));
            ne++;
        }
        #pragma unroll
        for (int off = 32; off > 0; off >>= 1) m = fmaxf(m, __shfl_xor(m, off));
        float s = 0.f; float ex[4];
        for (int k = 0; k < ne; k++) {
            ex[k] = __expf(__builtin_bit_cast(float, ev[k].y) - m);
            s += ex[k];
        }
        #pragma unroll
        for (int off = 32; off > 0; off >>= 1) s += __shfl_xor(s, off);
        float iS = 1.f / fmaxf(s, 1e-30f);
        for (int k = 0; k < ne; k++) {
            atomicAdd(&srow[ev[k].x], ex[k] * iS);
            atomicAdd(&crow[ev[k].x], 1.f);
        }
    }
    __syncthreads();
    #pragma unroll
    for (int j = 0; j < 16; j++) {
        int q = t + 256 * j;
        sacc[(size_t)b * Q + q] += srow[q];
        cacc[(size_t)b * Q + q] += crow[q];
    }
}

__global__ void k_finscores(float* __restrict__ sacc, const float* __restrict__ cacc) {
    int idx = blockIdx.x * 256 + threadIdx.x;
    sacc[idx] = sacc[idx] / fmaxf(cacc[idx], 1.f);
}

// block per b: logits row (pos + neg) scaled by 1/TAU
__global__ void k_logits(const float* __restrict__ query, const float* __restrict__ key,
                         const float* __restrict__ neg, float* __restrict__ out) {
    __shared__ float qrow[F];
    __shared__ float red[256];
    int b = blockIdx.x, t = threadIdx.x;
    float pp = 0.f;
    if (t < F) { float qv = query[b * F + t]; qrow[t] = qv; pp = qv * key[b * F + t]; }
    red[t] = pp;
    __syncthreads();
    for (int s = 128; s > 0; s >>= 1) { if (t < s) red[t] += red[t + s]; __syncthreads(); }
    float pos = red[0];
    float acc[16];
    #pragma unroll
    for (int j = 0; j < 16; j++) acc[j] = 0.f;
    for (int f = 0; f < F; f++) {
        float a = qrow[f];
        const float* np_ = neg + (size_t)f * Q + t;
        #pragma unroll
        for (int j = 0; j < 16; j++) acc[j] = fmaf(a, np_[256 * j], acc[j]);
    }
    float* row = out + O_LOGITS + (size_t)b * (Q + 1);
    #pragma unroll
    for (int j = 0; j < 16; j++) row[1 + t + 256 * j] = acc[j] * INV_TAU;
    if (t == 0) row[0] = pos * INV_TAU;
}

// block per b: moco part (full-row LSE - z0) and neg-only LSE
__global__ void k_rowstats(const float* __restrict__ out, float* __restrict__ moco_part,
                           float* __restrict__ nlse) {
    __shared__ float red[256];
    int b = blockIdx.x, t = threadIdx.x;
    const float* row = out + O_LOGITS + (size_t)b * (Q + 1);
    float m = -INFINITY, mn = -INFINITY;
    for (int j = 0; j < 17; j++) {
        int i = t + 256 * j;
        if (i < Q + 1) { float zz = row[i]; m = fmaxf(m, zz); if (i >= 1) mn = fmaxf(mn, zz); }
    }
    red[t] = m; __syncthreads();
    for (int s = 128; s > 0; s >>= 1) { if (t < s) red[t] = fmaxf(red[t], red[t + s]); __syncthreads(); }
    float M = red[0]; __syncthreads();
    red[t] = mn; __syncthreads();
    for (int s = 128; s > 0; s >>= 1) { if (t < s) red[t] = fmaxf(red[t], red[t + s]); __syncthreads(); }
    float Mn = red[0]; __syncthreads();
    float s1 = 0.f, s2 = 0.f;
    for (int j = 0; j < 17; j++) {
        int i = t + 256 * j;
        if (i < Q + 1) { float zz = row[i]; s1 += expf(zz - M); if (i >= 1) s2 += expf(zz - Mn); }
    }
    red[t] = s1; __syncthreads();
    for (int s = 128; s > 0; s >>= 1) { if (t < s) red[t] += red[t + s]; __syncthreads(); }
    float S = red[0]; __syncthreads();
    red[t] = s2; __syncthreads();
    for (int s = 128; s > 0; s >>= 1) { if (t < s) red[t] += red[t + s]; __syncthreads(); }
    float Sn = red[0];
    if (t == 0) { moco_part[b] = M + logf(S) - row[0]; nlse[b] = Mn + logf(Sn); }
}

// normalize unc (/E), bitonic sort 4096, median per np.quantile 'linear'
__global__ void k_median(float* __restrict__ unc, float* __restrict__ ubp) {
    __shared__ float sd[4096];
    int t = threadIdx.x;
    #pragma unroll
    for (int j = 0; j < 4; j++) {
        int q = t + 1024 * j;
        float u = unc[q] * (1.f / 128.f);
        unc[q] = u; sd[q] = u;
    }
    __syncthreads();
    for (int k = 2; k <= 4096; k <<= 1) {
        for (int j = k >> 1; j > 0; j >>= 1) {
            #pragma unroll
            for (int base = 0; base < 4; base++) {
                int i = t + 1024 * base;
                int ixj = i ^ j;
                if (ixj > i) {
                    bool up = ((i & k) == 0);
                    float x = sd[i], y = sd[ixj];
                    if ((x > y) == up) { sd[i] = y; sd[ixj] = x; }
                }
            }
            __syncthreads();
        }
    }
    if (t == 0) { float a = sd[2047], b2 = sd[2048]; ubp[0] = a + 0.5f * (b2 - a); }
}

// per (b, mode): argmax of scores among allowed q (lowest-index ties), mask + loss part
__global__ void k_select(float* __restrict__ out, const float* __restrict__ scores,
                         const float* __restrict__ unc, const float* __restrict__ ubp,
                         const float* __restrict__ nlse, float* __restrict__ easy_part,
                         float* __restrict__ hard_part) {
    __shared__ float rv[256];
    __shared__ int ri[256];
    __shared__ int bshare;
    int b = blockIdx.x, mode = blockIdx.y, t = threadIdx.x;
    float ub = ubp[0];
    float bv = -INFINITY; int bidx = Q;
    #pragma unroll
    for (int j = 0; j < 16; j++) {
        int q = t + 256 * j;
        float u = unc[q];
        bool ok = (mode == 0) ? (u <= ub) : (u >= ub);
        if (ok) {
            float v = scores[(size_t)b * Q + q];
            if (v > bv || (v == bv && q < bidx)) { bv = v; bidx = q; }
        }
    }
    rv[t] = bv; ri[t] = bidx; __syncthreads();
    for (int s = 128; s > 0; s >>= 1) {
        if (t < s) {
            float v2 = rv[t + s]; int i2 = ri[t + s];
            if (v2 > rv[t] || (v2 == rv[t] && i2 < ri[t])) { rv[t] = v2; ri[t] = i2; }
        }
        __syncthreads();
    }
    if (t == 0) {
        int best = ri[0]; bshare = best;
        float zz = out[O_LOGITS + (size_t)b * (Q + 1) + 1 + best];
        float loss = nlse[b] - zz;
        (mode == 0 ? easy_part : hard_part)[b] = loss;
    }
    __syncthreads();
    int best = bshare;
    float* mrow = out + (mode == 0 ? O_EMASK : O_HMASK) + (size_t)b * Q;
    #pragma unroll
    for (int j = 0; j < 16; j++) { int q = t + 256 * j; mrow[q] = (q == best) ? 1.f : 0.f; }
}

__global__ void k_scalars(const float* __restrict__ moco, const float* __restrict__ easyp,
                          const float* __restrict__ hardp, float* __restrict__ out) {
    __shared__ float red[256];
    int t = threadIdx.x;
    red[t] = moco[t]; __syncthreads();
    for (int s = 128; s > 0; s >>= 1) { if (t < s) red[t] += red[t + s]; __syncthreads(); }
    if (t == 0) out[O_MOCO] = red[0] / 256.f;
    __syncthreads();
    red[t] = easyp[t]; __syncthreads();
    for (int s = 128; s > 0; s >>= 1) { if (t < s) red[t] += red[t + s]; __syncthreads(); }
    if (t == 0) out[O_ELOSS] = red[0] / 256.f;
    __syncthreads();
    red[t] = hardp[t]; __syncthreads();
    for (int s = 128; s > 0; s >>= 1) { if (t < s) red[t] += red[t + s]; __syncthreads(); }
    if (t == 0) out[O_HLOSS] = red[0] / 256.f;
}

extern "C" void kernel_launch(void* const* d_in, const int* in_sizes, int n_in,
                              void* d_out, int out_size, void* d_ws, size_t ws_size,
                              hipStream_t stream) {
    const float* query   = (const float*)d_in[0];
    const float* key     = (const float*)d_in[1];
    const float* teacher = (const float*)d_in[2];
    const float* neg     = (const float*)d_in[3];
    const u8* mask_t     = (const u8*)d_in[4];
    const u8* mask_n     = (const u8*)d_in[5];
    const u8* score_mask = (const u8*)d_in[6];
    const u8* boot_mask  = (const u8*)d_in[7];
    float* out = (float*)d_out;
    float* ws  = (float*)d_ws;

    long ws_floats = (long)(ws_size / 4);
    int Ec = (int)((ws_floats - (long)W_ENT) / (long)(B * CAP * 2));
    if (Ec > E) Ec = E;
    if (Ec < 1) Ec = 1;

    u16* af = (u16*)(ws + W_AF);
    u32* pb = (u32*)(ws + W_PB);
    u32* ps = (u32*)(ws + W_PS);
    u32* pn = (u32*)(ws + W_PN);
    int* cnt_buf = (int*)(ws + W_CNTB);
    uint2* ent_buf = (uint2*)(ws + W_ENT);

    // zero scores + cnt + unc (contiguous 2101248 floats)
    k_zero<<<2101248 / 256, 256, 0, stream>>>(ws + W_SCORES);
    k_pack<<<dim3((E * B) / 64, Q / 512), 256, 0, stream>>>(boot_mask, pb, B);
    k_pack<<<dim3((E * B) / 64, Q / 512), 256, 0, stream>>>(score_mask, ps, B);
    k_pack<<<dim3((E * F) / 64, Q / 512), 256, 0, stream>>>(mask_n, pn, F);
    k_afrag<<<E * B, 128, 0, stream>>>(teacher, mask_t, af);
    k_invn<<<dim3(E, Q / 256), 256, 0, stream>>>(neg, mask_n, ws + W_INVN);
    k_logits<<<B, 256, 0, stream>>>(query, key, neg, out);
    k_rowstats<<<B, 256, 0, stream>>>(out, ws + W_MOCO, ws + W_NLSE);

    for (int e0 = 0; e0 < E; e0 += Ec) {
        int ecnt = (E - e0 < Ec) ? (E - e0) : Ec;
        k_zeroi<<<ecnt, 256, 0, stream>>>(cnt_buf);
        k_fused<<<dim3(QW, ecnt), 256, 0, stream>>>(
            af, neg, pn, ws + W_INVN, pb, ps, ws + W_UNC, ent_buf, cnt_buf, e0);
        k_scores<<<B, 256, 0, stream>>>(ent_buf, cnt_buf, ws + W_SCORES, ws + W_CNT, ecnt);
    }

    k_finscores<<<(B * Q) / 256, 256, 0, stream>>>(ws + W_SCORES, ws + W_CNT);
    k_median<<<1, 1024, 0, stream>>>(ws + W_UNC, ws + W_UB);
    k_select<<<dim3(B, 2), 256, 0, stream>>>(out, ws + W_SCORES, ws + W_UNC, ws + W_UB,
                                             ws + W_NLSE, ws + W_EASY, ws + W_HARD);
    k_scalars<<<1, 256, 0, stream>>>(ws + W_MOCO, ws + W_EASY, ws + W_HARD, out);
}

// Round 5
// 1429.249 us; speedup vs baseline: 1.4345x; 1.0093x over previous
//
#include <hip/hip_runtime.h>
#include <cmath>

typedef unsigned char u8;
typedef unsigned short u16;
typedef unsigned int u32;
typedef __attribute__((ext_vector_type(8))) short s8v;    // 8 bf16 = 4 VGPRs
typedef __attribute__((ext_vector_type(4))) float f32x4;  // MFMA acc

#define B 256
#define F 128
#define Q 4096
#define E 128
#define QW 128               // Q/32 words per row
#define INV_TAU 5.0f
#define CAP 256              // compact entries per (e,b); binomial(4096,1/32) max ~180

// ---- ws layout (offsets in floats) ----
#define W_SCORES 0u            // B*Q = 1048576
#define W_CNT    1048576u      // B*Q
#define W_UNC    2097152u      // 4096
#define W_NLSE   2101248u      // 256
#define W_MOCO   2101504u
#define W_EASY   2101760u
#define W_HARD   2102016u
#define W_UB     2102272u      // 1 (padded 256)
#define W_INVN   2102528u      // E*Q = 524288
#define W_AF     2626816u      // bf16 E*B*F -> 2097152 floats
#define W_PB     4723968u      // packed boot  E*QW*B words = 4194304
#define W_PS     8918272u      // packed smask E*QW*B words = 4194304
#define W_PN     13112576u     // packed mask_n E*QW*F words = 2097152
#define W_CNTB   15209728u     // Ec*256 ints (reserve 32768)
#define W_ENT    15242496u     // Ec*256*CAP uint2 -> Ec*131072 floats

// ---- out layout (floats) ----
#define O_MOCO   0u
#define O_LOGITS 1u            // (B, Q+1)
#define O_ELOSS  1048833u
#define O_EMASK  1048834u      // (B, Q)
#define O_HLOSS  2097410u
#define O_HMASK  2097411u      // (B, Q)

static __device__ __forceinline__ u16 f2bf(float x) {
    unsigned int u = __builtin_bit_cast(unsigned int, x);
    unsigned int r = (u + 0x7FFFu + ((u >> 16) & 1u)) >> 16;
    return (u16)r;
}

__global__ void k_zero(float4* __restrict__ p) {
    p[(size_t)blockIdx.x * 256 + threadIdx.x] = make_float4(0.f, 0.f, 0.f, 0.f);
}
__global__ void k_zeroi(int* __restrict__ p) {
    p[(size_t)blockIdx.x * 256 + threadIdx.x] = 0;
}

// ---- bit-pack bool mask (N rows x Q bytes) -> transposed words out[e][qw][r]
__global__ void __launch_bounds__(256) k_pack(const u8* __restrict__ in,
                                              u32* __restrict__ out, int Rin) {
    __shared__ u32 lds[64 * 133];
    int t = threadIdx.x;
    int r0 = blockIdx.x * 64;
    int q0 = blockIdx.y * 512;
    int qw0 = q0 >> 5;
    #pragma unroll
    for (int i = 0; i < 8; i++) {
        int w = i * 256 + t;               // uint4 index; 32 per row
        int row = w >> 5, c = w & 31;
        uint4 v = *(const uint4*)&in[(size_t)(r0 + row) * Q + q0 + c * 16];
        int base = row * 133 + c * 4;
        lds[base] = v.x; lds[base + 1] = v.y; lds[base + 2] = v.z; lds[base + 3] = v.w;
    }
    __syncthreads();
    int e = r0 / Rin, rr = r0 % Rin;
    #pragma unroll
    for (int k = 0; k < 4; k++) {
        int qw = (t >> 6) + k * 4;         // 0..15
        int r = t & 63;
        u32 w = 0;
        #pragma unroll
        for (int j = 0; j < 8; j++) {
            u32 u = lds[r * 133 + qw * 8 + j];
            w |= ((u & 1u) | ((u >> 7) & 2u) | ((u >> 14) & 4u) | ((u >> 21) & 8u)) << (j * 4);
        }
        out[((size_t)e * QW + qw0 + qw) * Rin + rr + r] = w;
    }
}

// one block (128 thr) per (e,b): masked l2-norm of teacher row -> bf16 A-fragments
__global__ void k_afrag(const float* __restrict__ teacher, const u8* __restrict__ mask_t,
                        u16* __restrict__ af) {
    int eb = blockIdx.x;
    int e  = eb >> 8;
    int b  = eb & (B - 1);
    int f  = threadIdx.x;
    float v = mask_t[(size_t)eb * F + f] ? 0.f : teacher[b * F + f];
    float ss = v * v;
    #pragma unroll
    for (int o = 32; o > 0; o >>= 1) ss += __shfl_down(ss, o);
    __shared__ float s2[2];
    if ((threadIdx.x & 63) == 0) s2[threadIdx.x >> 6] = ss;
    __syncthreads();
    float d = fmaxf(sqrtf(s2[0] + s2[1]), 1e-12f);
    float t = v / d;
    int bg = b >> 4, m = b & 15;
    int kb = f >> 5, quad = (f >> 3) & 3, j = f & 7;
    int lane = quad * 16 + m;
    af[((((size_t)e * 16 + bg) * 4 + kb) * 64 + lane) * 8 + j] = f2bf(t);
}

// per (e, 1024-q block): 1/(TAU*||masked neg col||) — packed mask in LDS, float4 neg
__global__ void __launch_bounds__(256) k_invn(const float* __restrict__ neg,
                                              const u32* __restrict__ pn,
                                              float* __restrict__ invn) {
    __shared__ u32 lds[32 * 128];          // 16 KB: [qw_local][f]
    int e = blockIdx.x, t = threadIdx.x;
    int qblk = blockIdx.y;                 // 0..3
    size_t base = ((size_t)e * QW + qblk * 32) * F;
    #pragma unroll
    for (int k = 0; k < 16; k++) lds[t + 256 * k] = pn[base + t + 256 * k];
    __syncthreads();
    int q0 = qblk * 1024 + t * 4;
    int qwl = (t * 4) >> 5;
    int sh = (t * 4) & 31;
    float s0 = 0.f, s1 = 0.f, s2 = 0.f, s3 = 0.f;
    #pragma unroll 4
    for (int f = 0; f < F; f++) {
        float4 v = *(const float4*)&neg[(size_t)f * Q + q0];
        u32 w = lds[qwl * 128 + f] >> sh;
        if (!(w & 1u)) s0 = fmaf(v.x, v.x, s0);
        if (!(w & 2u)) s1 = fmaf(v.y, v.y, s1);
        if (!(w & 4u)) s2 = fmaf(v.z, v.z, s2);
        if (!(w & 8u)) s3 = fmaf(v.w, v.w, s3);
    }
    float4 r;
    r.x = INV_TAU / fmaxf(sqrtf(s0), 1e-12f);
    r.y = INV_TAU / fmaxf(sqrtf(s1), 1e-12f);
    r.z = INV_TAU / fmaxf(sqrtf(s2), 1e-12f);
    r.w = INV_TAU / fmaxf(sqrtf(s3), 1e-12f);
    *(float4*)&invn[(size_t)e * Q + q0] = r;
}

// Fused: per (e, 32-q slab): B-frags inline, MFMA in registers, cross-lane column
// softmax+entropy (boot bits), popc-reserved extraction of smask entries.
__global__ void __launch_bounds__(256) k_fused(
        const u16* __restrict__ af, const float* __restrict__ neg,
        const u32* __restrict__ pn, const float* __restrict__ invn,
        const u32* __restrict__ pb, const u32* __restrict__ ps,
        float* __restrict__ unc, uint2* __restrict__ ent_buf,
        int* __restrict__ cnt_buf, int e0) {
    __shared__ u16 bfrag[2][4][64 * 8];                       // 8 KB
    __shared__ __align__(16) u32 bword[256];
    __shared__ __align__(16) u32 sword[256];
    __shared__ int sbase[256];
    __shared__ float mstat[4][32], sstat[4][32], cstat[4][32], estat[4][32];
    __shared__ float carr[32];

    int qb = blockIdx.x;
    int el = blockIdx.y, e = e0 + el;
    int t = threadIdx.x;
    int q0 = qb * 32;

    bword[t] = pb[((size_t)e * QW + qb) * B + t];
    sword[t] = ps[((size_t)e * QW + qb) * B + t];

    // ---- stage B fragments (512 slots, 2/thread) ----
    #pragma unroll
    for (int s = 0; s < 2; s++) {
        int slot = t + 256 * s;
        int qg = slot >> 8;
        int r = slot & 255;
        int kb = r >> 6, lane2 = r & 63;
        int q = q0 + qg * 16 + (lane2 & 15);
        int fb = kb * 32 + (lane2 >> 4) * 8;
        float iv = invn[e * Q + q];
        u16 tmp[8];
        #pragma unroll
        for (int j = 0; j < 8; j++) {
            u32 bit = (pn[((size_t)e * QW + qb) * F + fb + j] >> (q & 31)) & 1u;
            float v = bit ? 0.f : neg[(size_t)(fb + j) * Q + q] * iv;
            tmp[j] = f2bf(v);
        }
        *(s8v*)&bfrag[qg][kb][lane2 * 8] = *(const s8v*)tmp;
    }
    __syncthreads();

    // ---- MFMA: wave w covers b in [w*64, w*64+64), both qg columns ----
    int wave = t >> 6, lane = t & 63;
    int colb = lane & 15, quad = lane >> 4;
    f32x4 acc[4][2];
    #pragma unroll
    for (int bgi = 0; bgi < 4; bgi++) {
        int bg = wave * 4 + bgi;
        s8v a[4];
        #pragma unroll
        for (int kb = 0; kb < 4; kb++)
            a[kb] = *(const s8v*)&af[((((size_t)e * 16 + bg) * 4 + kb) * 64 + lane) * 8];
        #pragma unroll
        for (int qg = 0; qg < 2; qg++) {
            f32x4 c4 = {0.f, 0.f, 0.f, 0.f};
            #pragma unroll
            for (int kb = 0; kb < 4; kb++) {
                s8v bv = *(const s8v*)&bfrag[qg][kb][lane * 8];
                c4 = __builtin_amdgcn_mfma_f32_16x16x32_bf16(a[kb], bv, c4, 0, 0, 0);
            }
            acc[bgi][qg] = c4;
        }
    }

    u32 bwr[4][4];
    #pragma unroll
    for (int bgi = 0; bgi < 4; bgi++) {
        int b0 = (wave * 4 + bgi) * 16 + quad * 4;
        uint4 v = *(const uint4*)&bword[b0];
        bwr[bgi][0] = v.x; bwr[bgi][1] = v.y; bwr[bgi][2] = v.z; bwr[bgi][3] = v.w;
    }

    // ---- phase A: masked max per column ----
    float mloc[2] = {-INFINITY, -INFINITY};
    #pragma unroll
    for (int bgi = 0; bgi < 4; bgi++)
        #pragma unroll
        for (int r = 0; r < 4; r++)
            #pragma unroll
            for (int qg = 0; qg < 2; qg++)
                if ((bwr[bgi][r] >> (qg * 16 + colb)) & 1u)
                    mloc[qg] = fmaxf(mloc[qg], acc[bgi][qg][r]);
    #pragma unroll
    for (int qg = 0; qg < 2; qg++) {
        mloc[qg] = fmaxf(mloc[qg], __shfl_xor(mloc[qg], 16));
        mloc[qg] = fmaxf(mloc[qg], __shfl_xor(mloc[qg], 32));
    }
    if (quad == 0) { mstat[wave][colb] = mloc[0]; mstat[wave][16 + colb] = mloc[1]; }
    __syncthreads();
    float Mg[2];
    #pragma unroll
    for (int qg = 0; qg < 2; qg++) {
        int col = qg * 16 + colb;
        float M = fmaxf(fmaxf(mstat[0][col], mstat[1][col]),
                        fmaxf(mstat[2][col], mstat[3][col]));
        Mg[qg] = (M == -INFINITY) ? 0.f : M;
    }

    // ---- phase B: masked exp-sum + count (exps cached in regs) ----
    float ex[4][2][4];
    float sloc[2] = {0.f, 0.f}, cloc[2] = {0.f, 0.f};
    #pragma unroll
    for (int bgi = 0; bgi < 4; bgi++)
        #pragma unroll
        for (int r = 0; r < 4; r++)
            #pragma unroll
            for (int qg = 0; qg < 2; qg++) {
                bool mk = (bwr[bgi][r] >> (qg * 16 + colb)) & 1u;
                float v = mk ? __expf(acc[bgi][qg][r] - Mg[qg]) : 0.f;
                ex[bgi][qg][r] = v;
                sloc[qg] += v;
                cloc[qg] += mk ? 1.f : 0.f;
            }
    #pragma unroll
    for (int qg = 0; qg < 2; qg++) {
        sloc[qg] += __shfl_xor(sloc[qg], 16); sloc[qg] += __shfl_xor(sloc[qg], 32);
        cloc[qg] += __shfl_xor(cloc[qg], 16); cloc[qg] += __shfl_xor(cloc[qg], 32);
    }
    if (quad == 0) {
        sstat[wave][colb] = sloc[0]; sstat[wave][16 + colb] = sloc[1];
        cstat[wave][colb] = cloc[0]; cstat[wave][16 + colb] = cloc[1];
    }
    __syncthreads();
    float invS[2];
    #pragma unroll
    for (int qg = 0; qg < 2; qg++) {
        int col = qg * 16 + colb;
        float S = sstat[0][col] + sstat[1][col] + sstat[2][col] + sstat[3][col];
        invS[qg] = 1.f / fmaxf(S, 1e-30f);
        if (wave == 0 && quad == 0)
            carr[col] = cstat[0][col] + cstat[1][col] + cstat[2][col] + cstat[3][col];
    }

    // ---- phase C: entropy (reuse cached exps) ----
    const float P0 = 1e-7f;
    const float C0 = 1.61180954e-6f;      // -P0*log(P0)
    float eloc[2] = {0.f, 0.f};
    #pragma unroll
    for (int bgi = 0; bgi < 4; bgi++)
        #pragma unroll
        for (int r = 0; r < 4; r++)
            #pragma unroll
            for (int qg = 0; qg < 2; qg++) {
                if ((bwr[bgi][r] >> (qg * 16 + colb)) & 1u) {
                    float p = ex[bgi][qg][r] * invS[qg] + P0;
                    eloc[qg] -= p * __logf(p);
                } else {
                    eloc[qg] += C0;
                }
            }
    #pragma unroll
    for (int qg = 0; qg < 2; qg++) {
        eloc[qg] += __shfl_xor(eloc[qg], 16); eloc[qg] += __shfl_xor(eloc[qg], 32);
    }
    if (quad == 0) { estat[wave][colb] = eloc[0]; estat[wave][16 + colb] = eloc[1]; }

    // ---- extraction reservation (per-b popc) ----
    {
        u32 sw = sword[t];
        int n = __popc(sw);
        int base = 0;
        if (n) base = atomicAdd(&cnt_buf[el * B + t], n);
        sbase[t] = base;
    }
    __syncthreads();

    if (t < 32) {
        float tot = estat[0][t] + estat[1][t] + estat[2][t] + estat[3][t];
        atomicAdd(&unc[q0 + t], tot / fmaxf(carr[t], 1.f));
    }

    // ---- scatter compact entries ----
    #pragma unroll
    for (int bgi = 0; bgi < 4; bgi++) {
        int b0 = (wave * 4 + bgi) * 16 + quad * 4;
        uint4 sv = *(const uint4*)&sword[b0];
        u32 svr[4] = {sv.x, sv.y, sv.z, sv.w};
        #pragma unroll
        for (int r = 0; r < 4; r++)
            #pragma unroll
            for (int qg = 0; qg < 2; qg++) {
                int c = qg * 16 + colb;
                u32 w = svr[r];
                if ((w >> c) & 1u) {
                    int pos = sbase[b0 + r] + __popc(w & ((1u << c) - 1u));
                    if (pos < CAP) {
                        uint2 en;
                        en.x = (unsigned)(q0 + c);
                        en.y = __builtin_bit_cast(unsigned, acc[bgi][qg][r]);
                        ent_buf[((size_t)(el * B + b0 + r)) * CAP + pos] = en;
                    }
                }
            }
    }
}

// block per b: wave-per-el replay of compact entries -> row softmax -> scores/cnt
__global__ void __launch_bounds__(256) k_scores(
        const uint2* __restrict__ ent_buf, const int* __restrict__ cnt_buf,
        float* __restrict__ sacc, float* __restrict__ cacc, int ecnt) {
    __shared__ float srow[Q];
    __shared__ float crow[Q];
    int b = blockIdx.x, t = threadIdx.x;
    #pragma unroll
    for (int j = 0; j < 16; j++) { srow[t + 256 * j] = 0.f; crow[t + 256 * j] = 0.f; }
    __syncthreads();
    int wave = t >> 6, lane = t & 63;
    for (int el = wave; el < ecnt; el += 4) {
        int c = cnt_buf[el * B + b];
        if (c > CAP) c = CAP;
        if (c == 0) continue;
        const uint2* p = ent_buf + (size_t)(el * B + b) * CAP;
        uint2 ev[4]; int ne = 0;
        float m = -INFINITY;
        for (int i = lane; i < c; i += 64) {
            ev[ne] = p[i];
            m = fmaxf(m, __builtin_bit_cast(float, ev[ne].y));
            ne++;
        }
        #pragma unroll
        for (int off = 32; off > 0; off >>= 1) m = fmaxf(m, __shfl_xor(m, off));
        float s = 0.f; float exv[4];
        for (int k = 0; k < ne; k++) {
            exv[k] = __expf(__builtin_bit_cast(float, ev[k].y) - m);
            s += exv[k];
        }
        #pragma unroll
        for (int off = 32; off > 0; off >>= 1) s += __shfl_xor(s, off);
        float iS = 1.f / fmaxf(s, 1e-30f);
        for (int k = 0; k < ne; k++) {
            atomicAdd(&srow[ev[k].x], exv[k] * iS);
            atomicAdd(&crow[ev[k].x], 1.f);
        }
    }
    __syncthreads();
    #pragma unroll
    for (int j = 0; j < 16; j++) {
        int q = t + 256 * j;
        sacc[(size_t)b * Q + q] += srow[q];
        cacc[(size_t)b * Q + q] += crow[q];
    }
}

__global__ void k_finscores(float* __restrict__ sacc, const float* __restrict__ cacc) {
    int idx = blockIdx.x * 256 + threadIdx.x;
    sacc[idx] = sacc[idx] / fmaxf(cacc[idx], 1.f);
}

// block per b: logits row (pos + neg) scaled by 1/TAU — float4 loads
__global__ void k_logits(const float* __restrict__ query, const float* __restrict__ key,
                         const float* __restrict__ neg, float* __restrict__ out) {
    __shared__ float qrow[F];
    __shared__ float red[256];
    int b = blockIdx.x, t = threadIdx.x;
    float pp = 0.f;
    if (t < F) { float qv = query[b * F + t]; qrow[t] = qv; pp = qv * key[b * F + t]; }
    red[t] = pp;
    __syncthreads();
    for (int s = 128; s > 0; s >>= 1) { if (t < s) red[t] += red[t + s]; __syncthreads(); }
    float pos = red[0];
    float4 acc[4];
    #pragma unroll
    for (int j = 0; j < 4; j++) acc[j] = make_float4(0.f, 0.f, 0.f, 0.f);
    for (int f = 0; f < F; f++) {
        float a = qrow[f];
        const float* np_ = neg + (size_t)f * Q + t * 4;
        #pragma unroll
        for (int j = 0; j < 4; j++) {
            float4 v = *(const float4*)&np_[1024 * j];
            acc[j].x = fmaf(a, v.x, acc[j].x);
            acc[j].y = fmaf(a, v.y, acc[j].y);
            acc[j].z = fmaf(a, v.z, acc[j].z);
            acc[j].w = fmaf(a, v.w, acc[j].w);
        }
    }
    float* row = out + O_LOGITS + (size_t)b * (Q + 1);
    #pragma unroll
    for (int j = 0; j < 4; j++) {
        int q = t * 4 + 1024 * j;
        row[1 + q]     = acc[j].x * INV_TAU;
        row[1 + q + 1] = acc[j].y * INV_TAU;
        row[1 + q + 2] = acc[j].z * INV_TAU;
        row[1 + q + 3] = acc[j].w * INV_TAU;
    }
    if (t == 0) row[0] = pos * INV_TAU;
}

// block per b: moco part (full-row LSE - z0) and neg-only LSE
__global__ void k_rowstats(const float* __restrict__ out, float* __restrict__ moco_part,
                           float* __restrict__ nlse) {
    __shared__ float red[256];
    int b = blockIdx.x, t = threadIdx.x;
    const float* row = out + O_LOGITS + (size_t)b * (Q + 1);
    float m = -INFINITY, mn = -INFINITY;
    for (int j = 0; j < 17; j++) {
        int i = t + 256 * j;
        if (i < Q + 1) { float zz = row[i]; m = fmaxf(m, zz); if (i >= 1) mn = fmaxf(mn, zz); }
    }
    red[t] = m; __syncthreads();
    for (int s = 128; s > 0; s >>= 1) { if (t < s) red[t] = fmaxf(red[t], red[t + s]); __syncthreads(); }
    float M = red[0]; __syncthreads();
    red[t] = mn; __syncthreads();
    for (int s = 128; s > 0; s >>= 1) { if (t < s) red[t] = fmaxf(red[t], red[t + s]); __syncthreads(); }
    float Mn = red[0]; __syncthreads();
    float s1 = 0.f, s2 = 0.f;
    for (int j = 0; j < 17; j++) {
        int i = t + 256 * j;
        if (i < Q + 1) { float zz = row[i]; s1 += expf(zz - M); if (i >= 1) s2 += expf(zz - Mn); }
    }
    red[t] = s1; __syncthreads();
    for (int s = 128; s > 0; s >>= 1) { if (t < s) red[t] += red[t + s]; __syncthreads(); }
    float S = red[0]; __syncthreads();
    red[t] = s2; __syncthreads();
    for (int s = 128; s > 0; s >>= 1) { if (t < s) red[t] += red[t + s]; __syncthreads(); }
    float Sn = red[0];
    if (t == 0) { moco_part[b] = M + logf(S) - row[0]; nlse[b] = Mn + logf(Sn); }
}

// normalize unc (/E), bitonic sort 4096, median per np.quantile 'linear'
__global__ void k_median(float* __restrict__ unc, float* __restrict__ ubp) {
    __shared__ float sd[4096];
    int t = threadIdx.x;
    #pragma unroll
    for (int j = 0; j < 4; j++) {
        int q = t + 1024 * j;
        float u = unc[q] * (1.f / 128.f);
        unc[q] = u; sd[q] = u;
    }
    __syncthreads();
    for (int k = 2; k <= 4096; k <<= 1) {
        for (int j = k >> 1; j > 0; j >>= 1) {
            #pragma unroll
            for (int base = 0; base < 4; base++) {
                int i = t + 1024 * base;
                int ixj = i ^ j;
                if (ixj > i) {
                    bool up = ((i & k) == 0);
                    float x = sd[i], y = sd[ixj];
                    if ((x > y) == up) { sd[i] = y; sd[ixj] = x; }
                }
            }
            __syncthreads();
        }
    }
    if (t == 0) { float a = sd[2047], b2 = sd[2048]; ubp[0] = a + 0.5f * (b2 - a); }
}

// per (b, mode): argmax of scores among allowed q (lowest-index ties), mask + loss part
__global__ void k_select(float* __restrict__ out, const float* __restrict__ scores,
                         const float* __restrict__ unc, const float* __restrict__ ubp,
                         const float* __restrict__ nlse, float* __restrict__ easy_part,
                         float* __restrict__ hard_part) {
    __shared__ float rv[256];
    __shared__ int ri[256];
    __shared__ int bshare;
    int b = blockIdx.x, mode = blockIdx.y, t = threadIdx.x;
    float ub = ubp[0];
    float bv = -INFINITY; int bidx = Q;
    #pragma unroll
    for (int j = 0; j < 16; j++) {
        int q = t + 256 * j;
        float u = unc[q];
        bool ok = (mode == 0) ? (u <= ub) : (u >= ub);
        if (ok) {
            float v = scores[(size_t)b * Q + q];
            if (v > bv || (v == bv && q < bidx)) { bv = v; bidx = q; }
        }
    }
    rv[t] = bv; ri[t] = bidx; __syncthreads();
    for (int s = 128; s > 0; s >>= 1) {
        if (t < s) {
            float v2 = rv[t + s]; int i2 = ri[t + s];
            if (v2 > rv[t] || (v2 == rv[t] && i2 < ri[t])) { rv[t] = v2; ri[t] = i2; }
        }
        __syncthreads();
    }
    if (t == 0) {
        int best = ri[0]; bshare = best;
        float zz = out[O_LOGITS + (size_t)b * (Q + 1) + 1 + best];
        float loss = nlse[b] - zz;
        (mode == 0 ? easy_part : hard_part)[b] = loss;
    }
    __syncthreads();
    int best = bshare;
    float* mrow = out + (mode == 0 ? O_EMASK : O_HMASK) + (size_t)b * Q;
    #pragma unroll
    for (int j = 0; j < 16; j++) { int q = t + 256 * j; mrow[q] = (q == best) ? 1.f : 0.f; }
}

__global__ void k_scalars(const float* __restrict__ moco, const float* __restrict__ easyp,
                          const float* __restrict__ hardp, float* __restrict__ out) {
    __shared__ float red[256];
    int t = threadIdx.x;
    red[t] = moco[t]; __syncthreads();
    for (int s = 128; s > 0; s >>= 1) { if (t < s) red[t] += red[t + s]; __syncthreads(); }
    if (t == 0) out[O_MOCO] = red[0] / 256.f;
    __syncthreads();
    red[t] = easyp[t]; __syncthreads();
    for (int s = 128; s > 0; s >>= 1) { if (t < s) red[t] += red[t + s]; __syncthreads(); }
    if (t == 0) out[O_ELOSS] = red[0] / 256.f;
    __syncthreads();
    red[t] = hardp[t]; __syncthreads();
    for (int s = 128; s > 0; s >>= 1) { if (t < s) red[t] += red[t + s]; __syncthreads(); }
    if (t == 0) out[O_HLOSS] = red[0] / 256.f;
}

extern "C" void kernel_launch(void* const* d_in, const int* in_sizes, int n_in,
                              void* d_out, int out_size, void* d_ws, size_t ws_size,
                              hipStream_t stream) {
    const float* query   = (const float*)d_in[0];
    const float* key     = (const float*)d_in[1];
    const float* teacher = (const float*)d_in[2];
    const float* neg     = (const float*)d_in[3];
    const u8* mask_t     = (const u8*)d_in[4];
    const u8* mask_n     = (const u8*)d_in[5];
    const u8* score_mask = (const u8*)d_in[6];
    const u8* boot_mask  = (const u8*)d_in[7];
    float* out = (float*)d_out;
    float* ws  = (float*)d_ws;

    long ws_floats = (long)(ws_size / 4);
    int Ec = (int)((ws_floats - (long)W_ENT) / (long)(B * CAP * 2));
    if (Ec > E) Ec = E;
    if (Ec < 1) Ec = 1;

    u16* af = (u16*)(ws + W_AF);
    u32* pb = (u32*)(ws + W_PB);
    u32* ps = (u32*)(ws + W_PS);
    u32* pn = (u32*)(ws + W_PN);
    int* cnt_buf = (int*)(ws + W_CNTB);
    uint2* ent_buf = (uint2*)(ws + W_ENT);

    // zero scores + cnt + unc (contiguous 2101248 floats = 2052*256 float4)
    k_zero<<<2052, 256, 0, stream>>>((float4*)(ws + W_SCORES));
    k_pack<<<dim3((E * B) / 64, Q / 512), 256, 0, stream>>>(boot_mask, pb, B);
    k_pack<<<dim3((E * B) / 64, Q / 512), 256, 0, stream>>>(score_mask, ps, B);
    k_pack<<<dim3((E * F) / 64, Q / 512), 256, 0, stream>>>(mask_n, pn, F);
    k_afrag<<<E * B, 128, 0, stream>>>(teacher, mask_t, af);
    k_invn<<<dim3(E, 4), 256, 0, stream>>>(neg, pn, ws + W_INVN);
    k_logits<<<B, 256, 0, stream>>>(query, key, neg, out);
    k_rowstats<<<B, 256, 0, stream>>>(out, ws + W_MOCO, ws + W_NLSE);

    for (int e0 = 0; e0 < E; e0 += Ec) {
        int ecnt = (E - e0 < Ec) ? (E - e0) : Ec;
        k_zeroi<<<ecnt, 256, 0, stream>>>(cnt_buf);
        k_fused<<<dim3(QW, ecnt), 256, 0, stream>>>(
            af, neg, pn, ws + W_INVN, pb, ps, ws + W_UNC, ent_buf, cnt_buf, e0);
        k_scores<<<B, 256, 0, stream>>>(ent_buf, cnt_buf, ws + W_SCORES, ws + W_CNT, ecnt);
    }

    k_finscores<<<(B * Q) / 256, 256, 0, stream>>>(ws + W_SCORES, ws + W_CNT);
    k_median<<<1, 1024, 0, stream>>>(ws + W_UNC, ws + W_UB);
    k_select<<<dim3(B, 2), 256, 0, stream>>>(out, ws + W_SCORES, ws + W_UNC, ws + W_UB,
                                             ws + W_NLSE, ws + W_EASY, ws + W_HARD);
    k_scalars<<<1, 256, 0, stream>>>(ws + W_MOCO, ws + W_EASY, ws + W_HARD, out);
}

// Round 6
// 1401.975 us; speedup vs baseline: 1.4624x; 1.0195x over previous
//
#include <hip/hip_runtime.h>
#include <cmath>

typedef unsigned char u8;
typedef unsigned short u16;
typedef unsigned int u32;
typedef __attribute__((ext_vector_type(8))) short s8v;    // 8 bf16 = 4 VGPRs
typedef __attribute__((ext_vector_type(4))) float f32x4;  // MFMA acc

#define B 256
#define F 128
#define Q 4096
#define E 128
#define QW 128               // Q/32 words per row
#define INV_TAU 5.0f
#define CAP 256              // compact entries per (e,b); binomial(4096,1/32) max ~180

// ---- ws layout (offsets in floats) ----
#define W_SCORES 0u            // B*Q = 1048576
#define W_CNT    1048576u      // B*Q
#define W_UNC    2097152u      // 4096
#define W_NLSE   2101248u      // 256
#define W_MOCO   2101504u
#define W_EASY   2101760u
#define W_HARD   2102016u
#define W_UB     2102272u      // 1 (padded 256)
#define W_INVN   2102528u      // E*Q = 524288
#define W_AF     2626816u      // bf16 E*B*F -> 2097152 floats
#define W_PB     4723968u      // packed boot  E*QW*B words = 4194304
#define W_PS     8918272u      // packed smask E*QW*B words = 4194304
#define W_PN     13112576u     // packed mask_n E*QW*F words = 2097152
#define W_CNTB   15209728u     // Ec*256 ints (reserve 32768)
#define W_ENT    15242496u     // Ec*256*CAP uint2 -> Ec*131072 floats

// ---- out layout (floats) ----
#define O_MOCO   0u
#define O_LOGITS 1u            // (B, Q+1)
#define O_ELOSS  1048833u
#define O_EMASK  1048834u      // (B, Q)
#define O_HLOSS  2097410u
#define O_HMASK  2097411u      // (B, Q)

static __device__ __forceinline__ u16 f2bf(float x) {
    unsigned int u = __builtin_bit_cast(unsigned int, x);
    unsigned int r = (u + 0x7FFFu + ((u >> 16) & 1u)) >> 16;
    return (u16)r;
}

__global__ void k_zero(float4* __restrict__ p) {
    p[(size_t)blockIdx.x * 256 + threadIdx.x] = make_float4(0.f, 0.f, 0.f, 0.f);
}
__global__ void k_zeroi(int* __restrict__ p) {
    p[(size_t)blockIdx.x * 256 + threadIdx.x] = 0;
}

// ---- bit-pack bool mask (N rows x Q bytes) -> transposed words out[e][qw][r]
__global__ void __launch_bounds__(256) k_pack(const u8* __restrict__ in,
                                              u32* __restrict__ out, int Rin) {
    __shared__ u32 lds[64 * 133];
    int t = threadIdx.x;
    int r0 = blockIdx.x * 64;
    int q0 = blockIdx.y * 512;
    int qw0 = q0 >> 5;
    #pragma unroll
    for (int i = 0; i < 8; i++) {
        int w = i * 256 + t;               // uint4 index; 32 per row
        int row = w >> 5, c = w & 31;
        uint4 v = *(const uint4*)&in[(size_t)(r0 + row) * Q + q0 + c * 16];
        int base = row * 133 + c * 4;
        lds[base] = v.x; lds[base + 1] = v.y; lds[base + 2] = v.z; lds[base + 3] = v.w;
    }
    __syncthreads();
    int e = r0 / Rin, rr = r0 % Rin;
    #pragma unroll
    for (int k = 0; k < 4; k++) {
        int qw = (t >> 6) + k * 4;         // 0..15
        int r = t & 63;
        u32 w = 0;
        #pragma unroll
        for (int j = 0; j < 8; j++) {
            u32 u = lds[r * 133 + qw * 8 + j];
            w |= ((u & 1u) | ((u >> 7) & 2u) | ((u >> 14) & 4u) | ((u >> 21) & 8u)) << (j * 4);
        }
        out[((size_t)e * QW + qw0 + qw) * Rin + rr + r] = w;
    }
}

// one block (128 thr) per (e,b): masked l2-norm of teacher row -> bf16 A-fragments
__global__ void k_afrag(const float* __restrict__ teacher, const u8* __restrict__ mask_t,
                        u16* __restrict__ af) {
    int eb = blockIdx.x;
    int e  = eb >> 8;
    int b  = eb & (B - 1);
    int f  = threadIdx.x;
    float v = mask_t[(size_t)eb * F + f] ? 0.f : teacher[b * F + f];
    float ss = v * v;
    #pragma unroll
    for (int o = 32; o > 0; o >>= 1) ss += __shfl_down(ss, o);
    __shared__ float s2[2];
    if ((threadIdx.x & 63) == 0) s2[threadIdx.x >> 6] = ss;
    __syncthreads();
    float d = fmaxf(sqrtf(s2[0] + s2[1]), 1e-12f);
    float t = v / d;
    int bg = b >> 4, m = b & 15;
    int kb = f >> 5, quad = (f >> 3) & 3, j = f & 7;
    int lane = quad * 16 + m;
    af[((((size_t)e * 16 + bg) * 4 + kb) * 64 + lane) * 8 + j] = f2bf(t);
}

// per (e, 1024-q block): 1/(TAU*||masked neg col||) — packed mask in LDS, float4 neg
__global__ void __launch_bounds__(256) k_invn(const float* __restrict__ neg,
                                              const u32* __restrict__ pn,
                                              float* __restrict__ invn) {
    __shared__ u32 lds[32 * 128];          // 16 KB: [qw_local][f]
    int e = blockIdx.x, t = threadIdx.x;
    int qblk = blockIdx.y;                 // 0..3
    size_t base = ((size_t)e * QW + qblk * 32) * F;
    #pragma unroll
    for (int k = 0; k < 16; k++) lds[t + 256 * k] = pn[base + t + 256 * k];
    __syncthreads();
    int q0 = qblk * 1024 + t * 4;
    int qwl = (t * 4) >> 5;
    int sh = (t * 4) & 31;
    float s0 = 0.f, s1 = 0.f, s2 = 0.f, s3 = 0.f;
    #pragma unroll 4
    for (int f = 0; f < F; f++) {
        float4 v = *(const float4*)&neg[(size_t)f * Q + q0];
        u32 w = lds[qwl * 128 + f] >> sh;
        if (!(w & 1u)) s0 = fmaf(v.x, v.x, s0);
        if (!(w & 2u)) s1 = fmaf(v.y, v.y, s1);
        if (!(w & 4u)) s2 = fmaf(v.z, v.z, s2);
        if (!(w & 8u)) s3 = fmaf(v.w, v.w, s3);
    }
    float4 r;
    r.x = INV_TAU / fmaxf(sqrtf(s0), 1e-12f);
    r.y = INV_TAU / fmaxf(sqrtf(s1), 1e-12f);
    r.z = INV_TAU / fmaxf(sqrtf(s2), 1e-12f);
    r.w = INV_TAU / fmaxf(sqrtf(s3), 1e-12f);
    *(float4*)&invn[(size_t)e * Q + q0] = r;
}

// Fused: per (e, 64-q slab): B-frags inline, MFMA in registers (16 tiles),
// M=0 column softmax+entropy (|z|<=~5.2 so exp(z) is safe), popc-reserved extraction.
__global__ void __launch_bounds__(256) k_fused(
        const u16* __restrict__ af, const float* __restrict__ neg,
        const u32* __restrict__ pn, const float* __restrict__ invn,
        const u32* __restrict__ pb, const u32* __restrict__ ps,
        float* __restrict__ unc, uint2* __restrict__ ent_buf,
        int* __restrict__ cnt_buf, int e0) {
    __shared__ u16 bfrag[4][4][512];                          // 16 KB
    __shared__ u32 bw[2][256], sw[2][256];                    // 4 KB
    __shared__ u32 pnl[2][128];                               // 1 KB
    __shared__ float invl[64];
    __shared__ float sstat[4][64], cstat[4][64], estat[4][64];
    __shared__ float carr[64];
    __shared__ int sbase[256];

    int qb = blockIdx.x;                  // 0..63 (64-q slab)
    int el = blockIdx.y, e = e0 + el;
    int t = threadIdx.x;
    int q0 = qb * 64;
    int qw0 = qb * 2;

    bw[0][t] = pb[((size_t)e * QW + qw0) * B + t];
    bw[1][t] = pb[((size_t)e * QW + qw0 + 1) * B + t];
    sw[0][t] = ps[((size_t)e * QW + qw0) * B + t];
    sw[1][t] = ps[((size_t)e * QW + qw0 + 1) * B + t];
    if (t < 128) {
        pnl[0][t] = pn[((size_t)e * QW + qw0) * F + t];
        pnl[1][t] = pn[((size_t)e * QW + qw0 + 1) * F + t];
    } else if (t < 192) {
        invl[t - 128] = invn[(size_t)e * Q + q0 + (t - 128)];
    }
    __syncthreads();

    // ---- stage B fragments (1024 slots, 4/thread) ----
    #pragma unroll
    for (int s = 0; s < 4; s++) {
        int slot = t + 256 * s;
        int qg = slot >> 8;
        int r = slot & 255;
        int kb = r >> 6, lane2 = r & 63;
        int ql = qg * 16 + (lane2 & 15);
        int fb = kb * 32 + (lane2 >> 4) * 8;
        float iv = invl[ql];
        const u32* pw = pnl[ql >> 5];
        int sh = ql & 31;
        u16 tmp[8];
        #pragma unroll
        for (int j = 0; j < 8; j++) {
            u32 bit = (pw[fb + j] >> sh) & 1u;
            float v = bit ? 0.f : neg[(size_t)(fb + j) * Q + q0 + ql] * iv;
            tmp[j] = f2bf(v);
        }
        *(s8v*)&bfrag[qg][kb][lane2 * 8] = *(const s8v*)tmp;
    }
    __syncthreads();

    // ---- MFMA: wave w covers b in [w*64, w*64+64), 4 qg columns ----
    int wave = t >> 6, lane = t & 63;
    int colb = lane & 15, quad = lane >> 4;
    f32x4 acc[4][4];
    #pragma unroll
    for (int bgi = 0; bgi < 4; bgi++) {
        int bg = wave * 4 + bgi;
        s8v a[4];
        #pragma unroll
        for (int kb = 0; kb < 4; kb++)
            a[kb] = *(const s8v*)&af[((((size_t)e * 16 + bg) * 4 + kb) * 64 + lane) * 8];
        #pragma unroll
        for (int qg = 0; qg < 4; qg++) {
            f32x4 c4 = {0.f, 0.f, 0.f, 0.f};
            #pragma unroll
            for (int kb = 0; kb < 4; kb++) {
                s8v bv = *(const s8v*)&bfrag[qg][kb][lane * 8];
                c4 = __builtin_amdgcn_mfma_f32_16x16x32_bf16(a[kb], bv, c4, 0, 0, 0);
            }
            acc[bgi][qg] = c4;
        }
    }

    // ---- phase B: masked exp-sum + count (M = 0) ----
    float sloc[4] = {0.f, 0.f, 0.f, 0.f}, cloc[4] = {0.f, 0.f, 0.f, 0.f};
    #pragma unroll
    for (int bgi = 0; bgi < 4; bgi++) {
        int b0 = (wave * 4 + bgi) * 16 + quad * 4;
        uint4 w0 = *(const uint4*)&bw[0][b0];
        uint4 w1 = *(const uint4*)&bw[1][b0];
        u32 W0[4] = {w0.x, w0.y, w0.z, w0.w};
        u32 W1[4] = {w1.x, w1.y, w1.z, w1.w};
        #pragma unroll
        for (int r = 0; r < 4; r++)
            #pragma unroll
            for (int qg = 0; qg < 4; qg++) {
                u32 w = (qg & 2) ? W1[r] : W0[r];
                int bpos = (qg & 1) * 16 + colb;
                if ((w >> bpos) & 1u) {
                    sloc[qg] += __expf(acc[bgi][qg][r]);
                    cloc[qg] += 1.f;
                }
            }
    }
    #pragma unroll
    for (int qg = 0; qg < 4; qg++) {
        sloc[qg] += __shfl_xor(sloc[qg], 16); sloc[qg] += __shfl_xor(sloc[qg], 32);
        cloc[qg] += __shfl_xor(cloc[qg], 16); cloc[qg] += __shfl_xor(cloc[qg], 32);
    }
    if (quad == 0)
        #pragma unroll
        for (int qg = 0; qg < 4; qg++) {
            sstat[wave][qg * 16 + colb] = sloc[qg];
            cstat[wave][qg * 16 + colb] = cloc[qg];
        }
    __syncthreads();
    float invS[4];
    #pragma unroll
    for (int qg = 0; qg < 4; qg++) {
        int c = qg * 16 + colb;
        float S = sstat[0][c] + sstat[1][c] + sstat[2][c] + sstat[3][c];
        invS[qg] = 1.f / fmaxf(S, 1e-30f);
    }
    if (wave == 0 && quad == 0)
        #pragma unroll
        for (int qg = 0; qg < 4; qg++) {
            int c = qg * 16 + colb;
            carr[c] = cstat[0][c] + cstat[1][c] + cstat[2][c] + cstat[3][c];
        }

    // ---- phase C: entropy ----
    const float P0 = 1e-7f;
    const float C0 = 1.61180954e-6f;      // -P0*log(P0)
    float eloc[4] = {0.f, 0.f, 0.f, 0.f};
    #pragma unroll
    for (int bgi = 0; bgi < 4; bgi++) {
        int b0 = (wave * 4 + bgi) * 16 + quad * 4;
        uint4 w0 = *(const uint4*)&bw[0][b0];
        uint4 w1 = *(const uint4*)&bw[1][b0];
        u32 W0[4] = {w0.x, w0.y, w0.z, w0.w};
        u32 W1[4] = {w1.x, w1.y, w1.z, w1.w};
        #pragma unroll
        for (int r = 0; r < 4; r++)
            #pragma unroll
            for (int qg = 0; qg < 4; qg++) {
                u32 w = (qg & 2) ? W1[r] : W0[r];
                int bpos = (qg & 1) * 16 + colb;
                if ((w >> bpos) & 1u) {
                    float p = __expf(acc[bgi][qg][r]) * invS[qg] + P0;
                    eloc[qg] -= p * __logf(p);
                } else {
                    eloc[qg] += C0;
                }
            }
    }
    #pragma unroll
    for (int qg = 0; qg < 4; qg++) {
        eloc[qg] += __shfl_xor(eloc[qg], 16); eloc[qg] += __shfl_xor(eloc[qg], 32);
    }
    if (quad == 0)
        #pragma unroll
        for (int qg = 0; qg < 4; qg++) estat[wave][qg * 16 + colb] = eloc[qg];

    // ---- extraction reservation (per-b popc over both words) ----
    {
        u32 a0 = sw[0][t], a1 = sw[1][t];
        int n = __popc(a0) + __popc(a1);
        int base = 0;
        if (n) base = atomicAdd(&cnt_buf[el * B + t], n);
        sbase[t] = base;
    }
    __syncthreads();

    if (t < 64) {
        float tot = estat[0][t] + estat[1][t] + estat[2][t] + estat[3][t];
        atomicAdd(&unc[q0 + t], tot / fmaxf(carr[t], 1.f));
    }

    // ---- scatter compact entries ----
    #pragma unroll
    for (int bgi = 0; bgi < 4; bgi++) {
        int b0 = (wave * 4 + bgi) * 16 + quad * 4;
        uint4 s0 = *(const uint4*)&sw[0][b0];
        uint4 s1 = *(const uint4*)&sw[1][b0];
        u32 S0[4] = {s0.x, s0.y, s0.z, s0.w};
        u32 S1[4] = {s1.x, s1.y, s1.z, s1.w};
        #pragma unroll
        for (int r = 0; r < 4; r++) {
            int bs = sbase[b0 + r];
            int p0 = __popc(S0[r]);
            #pragma unroll
            for (int qg = 0; qg < 4; qg++) {
                int bpos = (qg & 1) * 16 + colb;
                u32 w = (qg & 2) ? S1[r] : S0[r];
                if ((w >> bpos) & 1u) {
                    int rank = __popc(w & ((1u << bpos) - 1u)) + ((qg & 2) ? p0 : 0);
                    int pos = bs + rank;
                    if (pos < CAP) {
                        uint2 en;
                        en.x = (unsigned)(q0 + qg * 16 + colb);
                        en.y = __builtin_bit_cast(unsigned, acc[bgi][qg][r]);
                        ent_buf[((size_t)(el * B + b0 + r)) * CAP + pos] = en;
                    }
                }
            }
        }
    }
}

// block per b: wave-per-el replay of compact entries -> row softmax (M=0) -> scores/cnt
__global__ void __launch_bounds__(256) k_scores(
        const uint2* __restrict__ ent_buf, const int* __restrict__ cnt_buf,
        float* __restrict__ sacc, float* __restrict__ cacc, int ecnt) {
    __shared__ float srow[Q];
    __shared__ float crow[Q];
    int b = blockIdx.x, t = threadIdx.x;
    #pragma unroll
    for (int j = 0; j < 16; j++) { srow[t + 256 * j] = 0.f; crow[t + 256 * j] = 0.f; }
    __syncthreads();
    int wave = t >> 6, lane = t & 63;
    for (int el = wave; el < ecnt; el += 4) {
        int c = cnt_buf[el * B + b];
        if (c > CAP) c = CAP;
        if (c == 0) continue;
        const uint2* p = ent_buf + (size_t)(el * B + b) * CAP;
        uint2 ev[4]; float exv[4]; int ne = 0;
        float s = 0.f;
        for (int i = lane; i < c; i += 64) {
            ev[ne] = p[i];
            exv[ne] = __expf(__builtin_bit_cast(float, ev[ne].y));   // |z| <= ~5.2
            s += exv[ne];
            ne++;
        }
        #pragma unroll
        for (int off = 32; off > 0; off >>= 1) s += __shfl_xor(s, off);
        float iS = 1.f / fmaxf(s, 1e-30f);
        for (int k = 0; k < ne; k++) {
            atomicAdd(&srow[ev[k].x], exv[k] * iS);
            atomicAdd(&crow[ev[k].x], 1.f);
        }
    }
    __syncthreads();
    #pragma unroll
    for (int j = 0; j < 16; j++) {
        int q = t + 256 * j;
        sacc[(size_t)b * Q + q] += srow[q];
        cacc[(size_t)b * Q + q] += crow[q];
    }
}

__global__ void k_finscores(float* __restrict__ sacc, const float* __restrict__ cacc) {
    int idx = blockIdx.x * 256 + threadIdx.x;
    sacc[idx] = sacc[idx] / fmaxf(cacc[idx], 1.f);
}

// (b, seg) grid: logits slab of 1024 q; seg 0 also writes pos logit
__global__ void k_logits(const float* __restrict__ query, const float* __restrict__ key,
                         const float* __restrict__ neg, float* __restrict__ out) {
    __shared__ float qrow[F];
    __shared__ float red[256];
    int b = blockIdx.x, seg = blockIdx.y, t = threadIdx.x;
    if (t < F) qrow[t] = query[b * F + t];
    __syncthreads();
    int q0 = seg * 1024 + t * 4;
    float4 acc = make_float4(0.f, 0.f, 0.f, 0.f);
    for (int f = 0; f < F; f++) {
        float a = qrow[f];
        float4 v = *(const float4*)&neg[(size_t)f * Q + q0];
        acc.x = fmaf(a, v.x, acc.x);
        acc.y = fmaf(a, v.y, acc.y);
        acc.z = fmaf(a, v.z, acc.z);
        acc.w = fmaf(a, v.w, acc.w);
    }
    float* row = out + O_LOGITS + (size_t)b * (Q + 1);
    row[1 + q0]     = acc.x * INV_TAU;
    row[1 + q0 + 1] = acc.y * INV_TAU;
    row[1 + q0 + 2] = acc.z * INV_TAU;
    row[1 + q0 + 3] = acc.w * INV_TAU;
    if (seg == 0) {
        float pp = (t < F) ? qrow[t] * key[b * F + t] : 0.f;
        red[t] = pp;
        __syncthreads();
        for (int s = 128; s > 0; s >>= 1) { if (t < s) red[t] += red[t + s]; __syncthreads(); }
        if (t == 0) row[0] = red[0] * INV_TAU;
    }
}

// block per b: moco part (full-row LSE - z0) and neg-only LSE (logits NOT bounded -> keep max)
__global__ void k_rowstats(const float* __restrict__ out, float* __restrict__ moco_part,
                           float* __restrict__ nlse) {
    __shared__ float red[256];
    int b = blockIdx.x, t = threadIdx.x;
    const float* row = out + O_LOGITS + (size_t)b * (Q + 1);
    float m = -INFINITY, mn = -INFINITY;
    for (int j = 0; j < 17; j++) {
        int i = t + 256 * j;
        if (i < Q + 1) { float zz = row[i]; m = fmaxf(m, zz); if (i >= 1) mn = fmaxf(mn, zz); }
    }
    red[t] = m; __syncthreads();
    for (int s = 128; s > 0; s >>= 1) { if (t < s) red[t] = fmaxf(red[t], red[t + s]); __syncthreads(); }
    float M = red[0]; __syncthreads();
    red[t] = mn; __syncthreads();
    for (int s = 128; s > 0; s >>= 1) { if (t < s) red[t] = fmaxf(red[t], red[t + s]); __syncthreads(); }
    float Mn = red[0]; __syncthreads();
    float s1 = 0.f, s2 = 0.f;
    for (int j = 0; j < 17; j++) {
        int i = t + 256 * j;
        if (i < Q + 1) { float zz = row[i]; s1 += expf(zz - M); if (i >= 1) s2 += expf(zz - Mn); }
    }
    red[t] = s1; __syncthreads();
    for (int s = 128; s > 0; s >>= 1) { if (t < s) red[t] += red[t + s]; __syncthreads(); }
    float S = red[0]; __syncthreads();
    red[t] = s2; __syncthreads();
    for (int s = 128; s > 0; s >>= 1) { if (t < s) red[t] += red[t + s]; __syncthreads(); }
    float Sn = red[0];
    if (t == 0) { moco_part[b] = M + logf(S) - row[0]; nlse[b] = Mn + logf(Sn); }
}

// normalize unc (/E), bitonic sort 4096, median per np.quantile 'linear'
__global__ void k_median(float* __restrict__ unc, float* __restrict__ ubp) {
    __shared__ float sd[4096];
    int t = threadIdx.x;
    #pragma unroll
    for (int j = 0; j < 4; j++) {
        int q = t + 1024 * j;
        float u = unc[q] * (1.f / 128.f);
        unc[q] = u; sd[q] = u;
    }
    __syncthreads();
    for (int k = 2; k <= 4096; k <<= 1) {
        for (int j = k >> 1; j > 0; j >>= 1) {
            #pragma unroll
            for (int base = 0; base < 4; base++) {
                int i = t + 1024 * base;
                int ixj = i ^ j;
                if (ixj > i) {
                    bool up = ((i & k) == 0);
                    float x = sd[i], y = sd[ixj];
                    if ((x > y) == up) { sd[i] = y; sd[ixj] = x; }
                }
            }
            __syncthreads();
        }
    }
    if (t == 0) { float a = sd[2047], b2 = sd[2048]; ubp[0] = a + 0.5f * (b2 - a); }
}

// per (b, mode): argmax of scores among allowed q (lowest-index ties), mask + loss part
__global__ void k_select(float* __restrict__ out, const float* __restrict__ scores,
                         const float* __restrict__ unc, const float* __restrict__ ubp,
                         const float* __restrict__ nlse, float* __restrict__ easy_part,
                         float* __restrict__ hard_part) {
    __shared__ float rv[256];
    __shared__ int ri[256];
    __shared__ int bshare;
    int b = blockIdx.x, mode = blockIdx.y, t = threadIdx.x;
    float ub = ubp[0];
    float bv = -INFINITY; int bidx = Q;
    #pragma unroll
    for (int j = 0; j < 16; j++) {
        int q = t + 256 * j;
        float u = unc[q];
        bool ok = (mode == 0) ? (u <= ub) : (u >= ub);
        if (ok) {
            float v = scores[(size_t)b * Q + q];
            if (v > bv || (v == bv && q < bidx)) { bv = v; bidx = q; }
        }
    }
    rv[t] = bv; ri[t] = bidx; __syncthreads();
    for (int s = 128; s > 0; s >>= 1) {
        if (t < s) {
            float v2 = rv[t + s]; int i2 = ri[t + s];
            if (v2 > rv[t] || (v2 == rv[t] && i2 < ri[t])) { rv[t] = v2; ri[t] = i2; }
        }
        __syncthreads();
    }
    if (t == 0) {
        int best = ri[0]; bshare = best;
        float zz = out[O_LOGITS + (size_t)b * (Q + 1) + 1 + best];
        float loss = nlse[b] - zz;
        (mode == 0 ? easy_part : hard_part)[b] = loss;
    }
    __syncthreads();
    int best = bshare;
    float* mrow = out + (mode == 0 ? O_EMASK : O_HMASK) + (size_t)b * Q;
    #pragma unroll
    for (int j = 0; j < 16; j++) { int q = t + 256 * j; mrow[q] = (q == best) ? 1.f : 0.f; }
}

__global__ void k_scalars(const float* __restrict__ moco, const float* __restrict__ easyp,
                          const float* __restrict__ hardp, float* __restrict__ out) {
    __shared__ float red[256];
    int t = threadIdx.x;
    red[t] = moco[t]; __syncthreads();
    for (int s = 128; s > 0; s >>= 1) { if (t < s) red[t] += red[t + s]; __syncthreads(); }
    if (t == 0) out[O_MOCO] = red[0] / 256.f;
    __syncthreads();
    red[t] = easyp[t]; __syncthreads();
    for (int s = 128; s > 0; s >>= 1) { if (t < s) red[t] += red[t + s]; __syncthreads(); }
    if (t == 0) out[O_ELOSS] = red[0] / 256.f;
    __syncthreads();
    red[t] = hardp[t]; __syncthreads();
    for (int s = 128; s > 0; s >>= 1) { if (t < s) red[t] += red[t + s]; __syncthreads(); }
    if (t == 0) out[O_HLOSS] = red[0] / 256.f;
}

extern "C" void kernel_launch(void* const* d_in, const int* in_sizes, int n_in,
                              void* d_out, int out_size, void* d_ws, size_t ws_size,
                              hipStream_t stream) {
    const float* query   = (const float*)d_in[0];
    const float* key     = (const float*)d_in[1];
    const float* teacher = (const float*)d_in[2];
    const float* neg     = (const float*)d_in[3];
    const u8* mask_t     = (const u8*)d_in[4];
    const u8* mask_n     = (const u8*)d_in[5];
    const u8* score_mask = (const u8*)d_in[6];
    const u8* boot_mask  = (const u8*)d_in[7];
    float* out = (float*)d_out;
    float* ws  = (float*)d_ws;

    long ws_floats = (long)(ws_size / 4);
    int Ec = (int)((ws_floats - (long)W_ENT) / (long)(B * CAP * 2));
    if (Ec > E) Ec = E;
    if (Ec < 1) Ec = 1;

    u16* af = (u16*)(ws + W_AF);
    u32* pb = (u32*)(ws + W_PB);
    u32* ps = (u32*)(ws + W_PS);
    u32* pn = (u32*)(ws + W_PN);
    int* cnt_buf = (int*)(ws + W_CNTB);
    uint2* ent_buf = (uint2*)(ws + W_ENT);

    // zero scores + cnt + unc (contiguous 2101248 floats = 2052*256 float4)
    k_zero<<<2052, 256, 0, stream>>>((float4*)(ws + W_SCORES));
    k_pack<<<dim3((E * B) / 64, Q / 512), 256, 0, stream>>>(boot_mask, pb, B);
    k_pack<<<dim3((E * B) / 64, Q / 512), 256, 0, stream>>>(score_mask, ps, B);
    k_pack<<<dim3((E * F) / 64, Q / 512), 256, 0, stream>>>(mask_n, pn, F);
    k_afrag<<<E * B, 128, 0, stream>>>(teacher, mask_t, af);
    k_invn<<<dim3(E, 4), 256, 0, stream>>>(neg, pn, ws + W_INVN);
    k_logits<<<dim3(B, 4), 256, 0, stream>>>(query, key, neg, out);
    k_rowstats<<<B, 256, 0, stream>>>(out, ws + W_MOCO, ws + W_NLSE);

    for (int e0 = 0; e0 < E; e0 += Ec) {
        int ecnt = (E - e0 < Ec) ? (E - e0) : Ec;
        k_zeroi<<<ecnt, 256, 0, stream>>>(cnt_buf);
        k_fused<<<dim3(Q / 64, ecnt), 256, 0, stream>>>(
            af, neg, pn, ws + W_INVN, pb, ps, ws + W_UNC, ent_buf, cnt_buf, e0);
        k_scores<<<B, 256, 0, stream>>>(ent_buf, cnt_buf, ws + W_SCORES, ws + W_CNT, ecnt);
    }

    k_finscores<<<(B * Q) / 256, 256, 0, stream>>>(ws + W_SCORES, ws + W_CNT);
    k_median<<<1, 1024, 0, stream>>>(ws + W_UNC, ws + W_UB);
    k_select<<<dim3(B, 2), 256, 0, stream>>>(out, ws + W_SCORES, ws + W_UNC, ws + W_UB,
                                             ws + W_NLSE, ws + W_EASY, ws + W_HARD);
    k_scalars<<<1, 256, 0, stream>>>(ws + W_MOCO, ws + W_EASY, ws + W_HARD, out);
}